// Round 5
// baseline (411.607 us; speedup 1.0000x reference)
//
#include <hip/hip_runtime.h>
#include <math.h>

#define S_LEN 2048
#define NHEAD 16
#define HDIM  64

typedef __attribute__((ext_vector_type(8))) short bf16x8;
typedef __attribute__((ext_vector_type(4))) float f32x4;

__device__ __forceinline__ unsigned short f2bf(float f) {
    union { float f; unsigned u; } v; v.f = f;
    unsigned r = v.u + 0x7fffu + ((v.u >> 16) & 1u);
    return (unsigned short)(r >> 16);
}
__device__ __forceinline__ float bf2f(unsigned short u) {
    union { unsigned u; float f; } v; v.u = ((unsigned)u) << 16;
    return v.f;
}

// async 16B global->LDS. LDS dest must be wave-uniform base + lane*16.
__device__ __forceinline__ void gl2lds16(const void* g, void* l) {
    __builtin_amdgcn_global_load_lds(
        (__attribute__((address_space(1))) void*)(void*)(g),
        (__attribute__((address_space(3))) void*)(l), 16, 0, 0);
}

// =====================================================================
// Kernel 0: fp32 -> bf16 convert. dst: hs[4M] | Wq[1M] | Wk[1M] | Wv[1M] | Wo[1M]
// =====================================================================
__global__ __launch_bounds__(256) void convert_kernel(
    const float* __restrict__ hs, const float* __restrict__ Wq,
    const float* __restrict__ Wk, const float* __restrict__ Wv,
    const float* __restrict__ Wo, unsigned short* __restrict__ dst)
{
    const int gid = blockIdx.x * 256 + threadIdx.x;
    const int n = gid << 2;
    const float* src; int off;
    if (n < (4 << 20))      { src = hs; off = n; }
    else if (n < (5 << 20)) { src = Wq; off = n - (4 << 20); }
    else if (n < (6 << 20)) { src = Wk; off = n - (5 << 20); }
    else if (n < (7 << 20)) { src = Wv; off = n - (6 << 20); }
    else                    { src = Wo; off = n - (7 << 20); }
    const float4 v = *(const float4*)(src + off);
    ushort4 o;
    o.x = f2bf(v.x); o.y = f2bf(v.y); o.z = f2bf(v.z); o.w = f2bf(v.w);
    *(ushort4*)(dst + n) = o;
}

// =====================================================================
// Kernel 1: QKV GEMM, bf16 MFMA 16x16x32, tile 128x128 BK=64, RoPE fused.
// =====================================================================
__global__ __launch_bounds__(256, 3) void qkv_gemm_kernel(
    const unsigned short* __restrict__ X,     // [4096][1024] bf16
    const unsigned short* __restrict__ Wall,  // wq|wk|wv (1M each)
    const float* __restrict__ bq, const float* __restrict__ bk,
    const float* __restrict__ bv,
    unsigned short* __restrict__ qo, unsigned short* __restrict__ ko,
    unsigned short* __restrict__ vo)
{
    __shared__ unsigned short As[128 * 64];
    __shared__ unsigned short Bs[128 * 64];

    const int mat = blockIdx.x >> 3;
    const int n0  = (blockIdx.x & 7) << 7;
    const int m0  = blockIdx.y << 7;
    const unsigned short* W = Wall + (mat << 20);
    const float* bias = (mat == 0) ? bq : (mat == 1) ? bk : bv;
    unsigned short* out = (mat == 0) ? qo : (mat == 1) ? ko : vo;

    const int tid = threadIdx.x;
    const int wave = tid >> 6, lane = tid & 63;
    const int quad = lane >> 4, ln = lane & 15;
    const int wm = (wave >> 1) << 6, wn = (wave & 1) << 6;

    f32x4 acc[4][4] = {};

    for (int k0 = 0; k0 < 1024; k0 += 64) {
        #pragma unroll
        for (int L = 0; L < 4; ++L) {
            const int i = tid + (L << 8);
            const int r = i >> 3, cl = i & 7;
            const int cg = (cl ^ (r & 7)) << 3;
            gl2lds16(X + (m0 + r) * 1024 + k0 + cg, &As[i << 3]);
            gl2lds16(W + (n0 + r) * 1024 + k0 + cg, &Bs[i << 3]);
        }
        __syncthreads();
        #pragma unroll
        for (int s = 0; s < 2; ++s) {
            bf16x8 a[4], b[4];
            #pragma unroll
            for (int t = 0; t < 4; ++t) {
                const int ra = wm + (t << 4) + ln;
                a[t] = *(const bf16x8*)&As[(ra << 6) + ((((s << 2) | quad) ^ (ra & 7)) << 3)];
                const int rb = wn + (t << 4) + ln;
                b[t] = *(const bf16x8*)&Bs[(rb << 6) + ((((s << 2) | quad) ^ (rb & 7)) << 3)];
            }
            #pragma unroll
            for (int i = 0; i < 4; ++i)
                #pragma unroll
                for (int j = 0; j < 4; ++j)
                    acc[i][j] = __builtin_amdgcn_mfma_f32_16x16x32_bf16(a[i], b[j], acc[i][j], 0, 0, 0);
        }
        __syncthreads();
    }

    float bv4[4];
    #pragma unroll
    for (int jt = 0; jt < 4; ++jt) bv4[jt] = bias[n0 + wn + (jt << 4) + ln];

    const float l2c = 0.41524101186092029f;  // log2(10000)/32
    const int h = (n0 + wn) >> 6;

    #pragma unroll
    for (int i = 0; i < 4; ++i) {
        #pragma unroll
        for (int reg = 0; reg < 4; ++reg) {
            const int m = m0 + wm + (i << 4) + (quad << 2) + reg;
            const int b_ = m >> 11, s_ = m & 2047;
            unsigned short* o = out + ((((b_ << 4) + h) << 11) + s_) * 64;
            if (mat < 2) {
                #pragma unroll
                for (int jl = 0; jl < 2; ++jl) {
                    const int hd = (jl << 4) + ln;     // 0..31
                    const float ang = (float)s_ * exp2f(-(float)hd * l2c);
                    float c, sn; sincosf(ang, &sn, &c);
                    const float x1 = acc[i][jl][reg] + bv4[jl];
                    const float x2 = acc[i][jl + 2][reg] + bv4[jl + 2];
                    o[hd]      = f2bf(x1 * c - x2 * sn);
                    o[hd + 32] = f2bf(x2 * c + x1 * sn);
                }
            } else {
                #pragma unroll
                for (int jt = 0; jt < 4; ++jt) {
                    const int hd = (jt << 4) + ln;
                    o[hd] = f2bf(acc[i][jt][reg] + bv4[jt]);
                }
            }
        }
    }
}

// =====================================================================
// Kernel 2: V transpose [B,H,S,HD] -> [B,H,HD,S], 64x64 tiles via LDS.
// =====================================================================
__global__ __launch_bounds__(256) void vtrans_kernel(
    const unsigned short* __restrict__ v, unsigned short* __restrict__ vt)
{
    __shared__ unsigned short T[64][66];
    const int bh = blockIdx.x >> 5;
    const int s0 = (blockIdx.x & 31) << 6;
    const int tid = threadIdx.x;
    #pragma unroll
    for (int L = 0; L < 4; ++L) {
        const int i = tid + (L << 8);
        const int r = i >> 4, c4 = (i & 15) << 2;
        const ushort4 in = *(const ushort4*)(v + ((bh << 11) + s0 + r) * 64 + c4);
        T[r][c4 + 0] = in.x; T[r][c4 + 1] = in.y;
        T[r][c4 + 2] = in.z; T[r][c4 + 3] = in.w;
    }
    __syncthreads();
    #pragma unroll
    for (int L = 0; L < 4; ++L) {
        const int i = tid + (L << 8);
        const int hd = i >> 4, c4 = (i & 15) << 2;
        ushort4 o;
        o.x = T[c4 + 0][hd]; o.y = T[c4 + 1][hd];
        o.z = T[c4 + 2][hd]; o.w = T[c4 + 3][hd];
        *(ushort4*)(vt + ((bh << 6) + hd) * 2048 + s0 + c4) = o;
    }
}

// =====================================================================
// Kernel 3: flash v3 — split-K (2-way) + XCD-affinity swizzle.
//  idx: bh = idx&31 (-> XCD = bh%8: one XCD's L2 holds only 4 bh's K/V),
//       sk = (idx>>5)&1 (K-range half), qt = idx>>6.
//  Each block: 64 q-rows x 1024 k. m==0 softmax (scores*scale+mask tiny),
//  unnormalized partial O (bf16) + l (fp32) to workspace; combine adds.
//  LDS 24KB, VGPR ~48 -> 6 blocks/CU; grid 2048 = 8 blocks/CU available.
// =====================================================================
__global__ __launch_bounds__(256, 6) void flash_kernel(
    const unsigned short* __restrict__ qb, const unsigned short* __restrict__ kb,
    const unsigned short* __restrict__ vtb, const float* __restrict__ mask,
    unsigned short* __restrict__ Opart, float* __restrict__ lpart)
{
    __shared__ unsigned short Ks[64 * 64];
    __shared__ unsigned short Vt[64 * 64];
    __shared__ unsigned short Ps[64 * 64];

    const int idx = blockIdx.x;
    const int bh = idx & 31;
    const int sk = (idx >> 5) & 1;
    const int qt = idx >> 6;
    const int b_ = bh >> 4;
    const int q0 = qt << 6;
    const int kstart = sk << 10;

    const int tid = threadIdx.x;
    const int wave = tid >> 6, lane = tid & 63;
    const int quad = lane >> 4, ln = lane & 15;

    // Q fragments in registers: rows q0+wave*16+ln
    const unsigned short* qrow = qb + ((size_t)((bh << 11) + q0 + (wave << 4) + ln) << 6);
    bf16x8 qa[2];
    qa[0] = *(const bf16x8*)(qrow + (quad << 3));
    qa[1] = *(const bf16x8*)(qrow + 32 + (quad << 3));

    const float LOG2E = 1.4426950408889634f;
    const float scale2 = (0.125f / logf(2048.0f)) * LOG2E;

    const float* mbase = mask + ((size_t)b_ << 22)
                       + ((size_t)(q0 + (wave << 4) + (quad << 2)) << 11) + ln;

    unsigned short* Pw = Ps + (wave << 10);

    float l_i[4] = {0.f, 0.f, 0.f, 0.f};
    f32x4 O[4] = {};

    // stage k-tile 0 of this split
    {
        #pragma unroll
        for (int L = 0; L < 2; ++L) {
            const int i = tid + (L << 8);
            const int r = i >> 3, cl = i & 7;
            const int cg = (cl ^ (r & 7)) << 3;
            gl2lds16(kb + ((bh << 11) + kstart + r) * 64 + cg, &Ks[i << 3]);
            gl2lds16(vtb + ((bh << 6) + r) * 2048 + kstart + cg, &Vt[i << 3]);
        }
    }

    for (int kt = 0; kt < 16; ++kt) {
        const int k0 = kstart + (kt << 6);

        // batch mask loads, fold 1/ln2
        float mreg[4][4];
        #pragma unroll
        for (int reg = 0; reg < 4; ++reg)
            #pragma unroll
            for (int j = 0; j < 4; ++j)
                mreg[reg][j] = mbase[(reg << 11) + k0 + (j << 4)] * LOG2E;

        __syncthreads();   // staging kt visible

        // S = Q K^T
        f32x4 sacc[4] = {};
        #pragma unroll
        for (int s = 0; s < 2; ++s) {
            bf16x8 bfr[4];
            #pragma unroll
            for (int j = 0; j < 4; ++j) {
                const int r = (j << 4) + ln;
                bfr[j] = *(const bf16x8*)&Ks[(r << 6) + ((((s << 2) | quad) ^ (r & 7)) << 3)];
            }
            #pragma unroll
            for (int j = 0; j < 4; ++j)
                sacc[j] = __builtin_amdgcn_mfma_f32_16x16x32_bf16(qa[s], bfr[j], sacc[j], 0, 0, 0);
        }

        // p = exp2(s*scale2 + mask*log2e)
        #pragma unroll
        for (int reg = 0; reg < 4; ++reg) {
            const int pr = (quad << 2) + reg;
            #pragma unroll
            for (int j = 0; j < 4; ++j) {
                const float p = exp2f(fmaf(sacc[j][reg], scale2, mreg[reg][j]));
                l_i[reg] += p;
                const int c = (j << 4) + ln;
                Pw[(pr << 6) + (((c >> 3) ^ (pr & 7)) << 3) + (c & 7)] = f2bf(p);
            }
        }

        // O += P V (P wave-private)
        #pragma unroll
        for (int s = 0; s < 2; ++s) {
            const bf16x8 a = *(const bf16x8*)&Pw[(ln << 6) + ((((s << 2) | quad) ^ (ln & 7)) << 3)];
            bf16x8 bfr[4];
            #pragma unroll
            for (int j = 0; j < 4; ++j) {
                const int r = (j << 4) + ln;
                bfr[j] = *(const bf16x8*)&Vt[(r << 6) + ((((s << 2) | quad) ^ (r & 7)) << 3)];
            }
            #pragma unroll
            for (int j = 0; j < 4; ++j)
                O[j] = __builtin_amdgcn_mfma_f32_16x16x32_bf16(a, bfr[j], O[j], 0, 0, 0);
        }

        __syncthreads();

        if (kt < 15) {
            const int kn = k0 + 64;
            #pragma unroll
            for (int L = 0; L < 2; ++L) {
                const int i = tid + (L << 8);
                const int r = i >> 3, cl = i & 7;
                const int cg = (cl ^ (r & 7)) << 3;
                gl2lds16(kb + ((bh << 11) + kn + r) * 64 + cg, &Ks[i << 3]);
                gl2lds16(vtb + ((bh << 6) + r) * 2048 + kn + cg, &Vt[i << 3]);
            }
        }
    }

    // partial epilogue: unnormalized O (bf16) + l (fp32)
    #pragma unroll
    for (int reg = 0; reg < 4; ++reg) {
        float l = l_i[reg];
        l += __shfl_xor(l, 1);
        l += __shfl_xor(l, 2);
        l += __shfl_xor(l, 4);
        l += __shfl_xor(l, 8);
        const int qr = q0 + (wave << 4) + (quad << 2) + reg;
        if (ln == 0) lpart[((sk << 5) + bh) * S_LEN + qr] = l;
        unsigned short* op = Opart + ((size_t)(((sk << 5) + bh) * S_LEN + qr) << 6);
        #pragma unroll
        for (int j = 0; j < 4; ++j)
            op[(j << 4) + ln] = f2bf(O[j][reg]);
    }
}

// =====================================================================
// Kernel 3b: combine split-K partials: attn = (O0+O1)/(l0+l1),
// dest layout [B,S,H,HD]. 1M threads x 4 elems.
// =====================================================================
__global__ __launch_bounds__(256) void combine_kernel(
    const unsigned short* __restrict__ Opart, const float* __restrict__ lpart,
    unsigned short* __restrict__ attnb)
{
    const int gid = blockIdx.x * 256 + threadIdx.x;
    const int hd4 = gid & 15;
    const int h   = (gid >> 4) & 15;
    const int s   = (gid >> 8) & 2047;
    const int b   = gid >> 19;
    const int bh  = (b << 4) + h;
    const size_t row = (size_t)bh * S_LEN + s;
    const size_t src = (row << 6) + (hd4 << 2);
    const ushort4 o0 = *(const ushort4*)(Opart + src);
    const ushort4 o1 = *(const ushort4*)(Opart + src + ((size_t)1 << 22));
    const float inv = 1.0f / (lpart[row] + lpart[(1 << 16) + row]);
    ushort4 o;
    o.x = f2bf((bf2f(o0.x) + bf2f(o1.x)) * inv);
    o.y = f2bf((bf2f(o0.y) + bf2f(o1.y)) * inv);
    o.z = f2bf((bf2f(o0.z) + bf2f(o1.z)) * inv);
    o.w = f2bf((bf2f(o0.w) + bf2f(o1.w)) * inv);
    *(ushort4*)(attnb + ((size_t)gid << 2)) = o;
}

// =====================================================================
// Kernel 4: out = attn @ Wo^T + bo, bf16 MFMA, fp32 out.
// =====================================================================
__global__ __launch_bounds__(256, 3) void out_gemm_kernel(
    const unsigned short* __restrict__ X, const unsigned short* __restrict__ W,
    const float* __restrict__ bias, float* __restrict__ out)
{
    __shared__ unsigned short As[128 * 64];
    __shared__ unsigned short Bs[128 * 64];

    const int n0 = blockIdx.x << 7;
    const int m0 = blockIdx.y << 7;
    const int tid = threadIdx.x;
    const int wave = tid >> 6, lane = tid & 63;
    const int quad = lane >> 4, ln = lane & 15;
    const int wm = (wave >> 1) << 6, wn = (wave & 1) << 6;

    f32x4 acc[4][4] = {};

    for (int k0 = 0; k0 < 1024; k0 += 64) {
        #pragma unroll
        for (int L = 0; L < 4; ++L) {
            const int i = tid + (L << 8);
            const int r = i >> 3, cl = i & 7;
            const int cg = (cl ^ (r & 7)) << 3;
            gl2lds16(X + (m0 + r) * 1024 + k0 + cg, &As[i << 3]);
            gl2lds16(W + (n0 + r) * 1024 + k0 + cg, &Bs[i << 3]);
        }
        __syncthreads();
        #pragma unroll
        for (int s = 0; s < 2; ++s) {
            bf16x8 a[4], b[4];
            #pragma unroll
            for (int t = 0; t < 4; ++t) {
                const int ra = wm + (t << 4) + ln;
                a[t] = *(const bf16x8*)&As[(ra << 6) + ((((s << 2) | quad) ^ (ra & 7)) << 3)];
                const int rb = wn + (t << 4) + ln;
                b[t] = *(const bf16x8*)&Bs[(rb << 6) + ((((s << 2) | quad) ^ (rb & 7)) << 3)];
            }
            #pragma unroll
            for (int i = 0; i < 4; ++i)
                #pragma unroll
                for (int j = 0; j < 4; ++j)
                    acc[i][j] = __builtin_amdgcn_mfma_f32_16x16x32_bf16(a[i], b[j], acc[i][j], 0, 0, 0);
        }
        __syncthreads();
    }

    float bv4[4];
    #pragma unroll
    for (int jt = 0; jt < 4; ++jt) bv4[jt] = bias[n0 + wn + (jt << 4) + ln];

    #pragma unroll
    for (int i = 0; i < 4; ++i)
        #pragma unroll
        for (int reg = 0; reg < 4; ++reg) {
            const int m = m0 + wm + (i << 4) + (quad << 2) + reg;
            #pragma unroll
            for (int jt = 0; jt < 4; ++jt) {
                const int n = n0 + wn + (jt << 4) + ln;
                out[m * 1024 + n] = acc[i][jt][reg] + bv4[jt];
            }
        }
}

// =====================================================================
extern "C" void kernel_launch(void* const* d_in, const int* in_sizes, int n_in,
                              void* d_out, int out_size, void* d_ws, size_t ws_size,
                              hipStream_t stream)
{
    const float* hs   = (const float*)d_in[0];
    const float* mask = (const float*)d_in[1];
    const float* Wq   = (const float*)d_in[2];
    const float* bq   = (const float*)d_in[3];
    const float* Wk   = (const float*)d_in[4];
    const float* bk   = (const float*)d_in[5];
    const float* Wv   = (const float*)d_in[6];
    const float* bv   = (const float*)d_in[7];
    const float* Wo   = (const float*)d_in[8];
    const float* bo   = (const float*)d_in[9];

    unsigned short* ws = (unsigned short*)d_ws;
    const size_t M1 = (size_t)1 << 20;
    unsigned short* hsb   = ws;               // 4M
    unsigned short* wall  = ws + 4 * M1;      // wq|wk|wv
    unsigned short* wob   = ws + 7 * M1;
    unsigned short* qbf   = ws + 8 * M1;
    unsigned short* kbf   = ws + 12 * M1;
    unsigned short* vbf   = ws + 16 * M1;
    unsigned short* vtb   = ws + 20 * M1;
    unsigned short* attnb = ws + 24 * M1;     // 4M
    unsigned short* Opart = ws + 28 * M1;     // 8M (2 splits x 4M)
    float*          lpart = (float*)(ws + 36 * M1);  // 2 x 64K floats

    convert_kernel<<<8192, 256, 0, stream>>>(hs, Wq, Wk, Wv, Wo, ws);
    qkv_gemm_kernel<<<dim3(24, 32), 256, 0, stream>>>(hsb, wall, bq, bk, bv, qbf, kbf, vbf);
    vtrans_kernel<<<1024, 256, 0, stream>>>(vbf, vtb);
    flash_kernel<<<2048, 256, 0, stream>>>(qbf, kbf, vtb, mask, Opart, lpart);
    combine_kernel<<<4096, 256, 0, stream>>>(Opart, lpart, attnb);
    out_gemm_kernel<<<dim3(8, 32), 256, 0, stream>>>(attnb, wob, bo, (float*)d_out);
}

// Round 6
// 250.754 us; speedup vs baseline: 1.6415x; 1.6415x over previous
//
#include <hip/hip_runtime.h>
#include <math.h>

#define S_LEN 2048
#define NHEAD 16
#define HDIM  64

typedef __attribute__((ext_vector_type(8))) short bf16x8;
typedef __attribute__((ext_vector_type(4))) float f32x4;

__device__ __forceinline__ unsigned short f2bf(float f) {
    union { float f; unsigned u; } v; v.f = f;
    unsigned r = v.u + 0x7fffu + ((v.u >> 16) & 1u);
    return (unsigned short)(r >> 16);
}

// async 16B global->LDS. LDS dest must be wave-uniform base + lane*16.
__device__ __forceinline__ void gl2lds16(const void* g, void* l) {
    __builtin_amdgcn_global_load_lds(
        (__attribute__((address_space(1))) void*)(void*)(g),
        (__attribute__((address_space(3))) void*)(l), 16, 0, 0);
}

// =====================================================================
// Kernel 0: fp32 -> bf16 convert. dst: hs[4M] | Wq[1M] | Wk[1M] | Wv[1M] | Wo[1M]
// =====================================================================
__global__ __launch_bounds__(256) void convert_kernel(
    const float* __restrict__ hs, const float* __restrict__ Wq,
    const float* __restrict__ Wk, const float* __restrict__ Wv,
    const float* __restrict__ Wo, unsigned short* __restrict__ dst)
{
    const int gid = blockIdx.x * 256 + threadIdx.x;
    const int n = gid << 2;
    const float* src; int off;
    if (n < (4 << 20))      { src = hs; off = n; }
    else if (n < (5 << 20)) { src = Wq; off = n - (4 << 20); }
    else if (n < (6 << 20)) { src = Wk; off = n - (5 << 20); }
    else if (n < (7 << 20)) { src = Wv; off = n - (6 << 20); }
    else                    { src = Wo; off = n - (7 << 20); }
    const float4 v = *(const float4*)(src + off);
    ushort4 o;
    o.x = f2bf(v.x); o.y = f2bf(v.y); o.z = f2bf(v.z); o.w = f2bf(v.w);
    *(ushort4*)(dst + n) = o;
}

// =====================================================================
// Kernel 1: QKV GEMM, bf16 MFMA 16x16x32, tile 128x128 BK=64, RoPE fused.
// =====================================================================
__global__ __launch_bounds__(256, 3) void qkv_gemm_kernel(
    const unsigned short* __restrict__ X,     // [4096][1024] bf16
    const unsigned short* __restrict__ Wall,  // wq|wk|wv (1M each)
    const float* __restrict__ bq, const float* __restrict__ bk,
    const float* __restrict__ bv,
    unsigned short* __restrict__ qo, unsigned short* __restrict__ ko,
    unsigned short* __restrict__ vo)
{
    __shared__ unsigned short As[128 * 64];
    __shared__ unsigned short Bs[128 * 64];

    const int mat = blockIdx.x >> 3;
    const int n0  = (blockIdx.x & 7) << 7;
    const int m0  = blockIdx.y << 7;
    const unsigned short* W = Wall + (mat << 20);
    const float* bias = (mat == 0) ? bq : (mat == 1) ? bk : bv;
    unsigned short* out = (mat == 0) ? qo : (mat == 1) ? ko : vo;

    const int tid = threadIdx.x;
    const int wave = tid >> 6, lane = tid & 63;
    const int quad = lane >> 4, ln = lane & 15;
    const int wm = (wave >> 1) << 6, wn = (wave & 1) << 6;

    f32x4 acc[4][4] = {};

    for (int k0 = 0; k0 < 1024; k0 += 64) {
        #pragma unroll
        for (int L = 0; L < 4; ++L) {
            const int i = tid + (L << 8);
            const int r = i >> 3, cl = i & 7;
            const int cg = (cl ^ (r & 7)) << 3;
            gl2lds16(X + (m0 + r) * 1024 + k0 + cg, &As[i << 3]);
            gl2lds16(W + (n0 + r) * 1024 + k0 + cg, &Bs[i << 3]);
        }
        __syncthreads();
        #pragma unroll
        for (int s = 0; s < 2; ++s) {
            bf16x8 a[4], b[4];
            #pragma unroll
            for (int t = 0; t < 4; ++t) {
                const int ra = wm + (t << 4) + ln;
                a[t] = *(const bf16x8*)&As[(ra << 6) + ((((s << 2) | quad) ^ (ra & 7)) << 3)];
                const int rb = wn + (t << 4) + ln;
                b[t] = *(const bf16x8*)&Bs[(rb << 6) + ((((s << 2) | quad) ^ (rb & 7)) << 3)];
            }
            #pragma unroll
            for (int i = 0; i < 4; ++i)
                #pragma unroll
                for (int j = 0; j < 4; ++j)
                    acc[i][j] = __builtin_amdgcn_mfma_f32_16x16x32_bf16(a[i], b[j], acc[i][j], 0, 0, 0);
        }
        __syncthreads();
    }

    float bv4[4];
    #pragma unroll
    for (int jt = 0; jt < 4; ++jt) bv4[jt] = bias[n0 + wn + (jt << 4) + ln];

    const float l2c = 0.41524101186092029f;  // log2(10000)/32
    const int h = (n0 + wn) >> 6;

    #pragma unroll
    for (int i = 0; i < 4; ++i) {
        #pragma unroll
        for (int reg = 0; reg < 4; ++reg) {
            const int m = m0 + wm + (i << 4) + (quad << 2) + reg;
            const int b_ = m >> 11, s_ = m & 2047;
            unsigned short* o = out + ((((b_ << 4) + h) << 11) + s_) * 64;
            if (mat < 2) {
                #pragma unroll
                for (int jl = 0; jl < 2; ++jl) {
                    const int hd = (jl << 4) + ln;     // 0..31
                    const float ang = (float)s_ * exp2f(-(float)hd * l2c);
                    float c, sn; sincosf(ang, &sn, &c);
                    const float x1 = acc[i][jl][reg] + bv4[jl];
                    const float x2 = acc[i][jl + 2][reg] + bv4[jl + 2];
                    o[hd]      = f2bf(x1 * c - x2 * sn);
                    o[hd + 32] = f2bf(x2 * c + x1 * sn);
                }
            } else {
                #pragma unroll
                for (int jt = 0; jt < 4; ++jt) {
                    const int hd = (jt << 4) + ln;
                    o[hd] = f2bf(acc[i][jt][reg] + bv4[jt]);
                }
            }
        }
    }
}

// =====================================================================
// Kernel 2: V transpose [B,H,S,HD] -> [B,H,HD,S], 64x64 tiles via LDS.
// =====================================================================
__global__ __launch_bounds__(256) void vtrans_kernel(
    const unsigned short* __restrict__ v, unsigned short* __restrict__ vt)
{
    __shared__ unsigned short T[64][66];
    const int bh = blockIdx.x >> 5;
    const int s0 = (blockIdx.x & 31) << 6;
    const int tid = threadIdx.x;
    #pragma unroll
    for (int L = 0; L < 4; ++L) {
        const int i = tid + (L << 8);
        const int r = i >> 4, c4 = (i & 15) << 2;
        const ushort4 in = *(const ushort4*)(v + ((bh << 11) + s0 + r) * 64 + c4);
        T[r][c4 + 0] = in.x; T[r][c4 + 1] = in.y;
        T[r][c4 + 2] = in.z; T[r][c4 + 3] = in.w;
    }
    __syncthreads();
    #pragma unroll
    for (int L = 0; L < 4; ++L) {
        const int i = tid + (L << 8);
        const int hd = i >> 4, c4 = (i & 15) << 2;
        ushort4 o;
        o.x = T[c4 + 0][hd]; o.y = T[c4 + 1][hd];
        o.z = T[c4 + 2][hd]; o.w = T[c4 + 3][hd];
        *(ushort4*)(vt + ((bh << 6) + hd) * 2048 + s0 + c4) = o;
    }
}

// =====================================================================
// Kernel 3: flash v4 — R3 structure + double-buffered K/V staging +
// mask register prefetch. Block order idx = bh*32+qt (KEEP: same-(b,qt)
// mask tile lands on one XCD -> L2 reuse across 16 heads; R4 proved the
// bh-low-bit order costs 5x FETCH).
//  * 64 q-rows/block, Q in registers, m==0 softmax, wave-private P.
//  * LDS: 2x(Ks+Vt) 32KB + Ps 8KB = 40KB -> 4 blocks/CU (= grid/CU).
//  * Per iter: 1 barrier; stage kt+1 + mask kt+1 issued right after it,
//    so the pre-barrier vmcnt(0) drain overlaps a full compute phase.
// =====================================================================
__global__ __launch_bounds__(256, 4) void flash_kernel(
    const unsigned short* __restrict__ qb, const unsigned short* __restrict__ kb,
    const unsigned short* __restrict__ vtb, const float* __restrict__ mask,
    unsigned short* __restrict__ attn)
{
    __shared__ unsigned short Ks[2][64 * 64];
    __shared__ unsigned short Vt[2][64 * 64];
    __shared__ unsigned short Ps[64 * 64];

    const int qt = blockIdx.x & 31;
    const int bh = blockIdx.x >> 5;
    const int b_ = bh >> 4, h = bh & 15;
    const int q0 = qt << 6;

    const int tid = threadIdx.x;
    const int wave = tid >> 6, lane = tid & 63;
    const int quad = lane >> 4, ln = lane & 15;

    // Q fragments in registers: rows q0+wave*16+ln
    const unsigned short* qrow = qb + ((size_t)((bh << 11) + q0 + (wave << 4) + ln) << 6);
    bf16x8 qa[2];
    qa[0] = *(const bf16x8*)(qrow + (quad << 3));
    qa[1] = *(const bf16x8*)(qrow + 32 + (quad << 3));

    const float LOG2E = 1.4426950408889634f;
    const float scale2 = (0.125f / logf(2048.0f)) * LOG2E;

    const float* mbase = mask + ((size_t)b_ << 22)
                       + ((size_t)(q0 + (wave << 4) + (quad << 2)) << 11) + ln;

    unsigned short* Pw = Ps + (wave << 10);

    float l_i[4] = {0.f, 0.f, 0.f, 0.f};
    f32x4 O[4] = {};

    // prologue: stage kt=0 -> buf0, mask[0] -> mcur
    #pragma unroll
    for (int L = 0; L < 2; ++L) {
        const int i = tid + (L << 8);
        const int r = i >> 3, cl = i & 7;
        const int cg = (cl ^ (r & 7)) << 3;
        gl2lds16(kb + ((bh << 11) + r) * 64 + cg, &Ks[0][i << 3]);
        gl2lds16(vtb + ((bh << 6) + r) * 2048 + cg, &Vt[0][i << 3]);
    }
    float mcur[4][4];
    #pragma unroll
    for (int reg = 0; reg < 4; ++reg)
        #pragma unroll
        for (int j = 0; j < 4; ++j)
            mcur[reg][j] = mbase[(reg << 11) + (j << 4)] * LOG2E;

    for (int kt = 0; kt < 32; ++kt) {
        const int cur = kt & 1;

        __syncthreads();   // buf[cur] staged; all waves done reading buf[cur^1]

        // issue next-iter staging + mask prefetch (completes during compute)
        float mnext[4][4];
        if (kt < 31) {
            const int kn = (kt + 1) << 6;
            #pragma unroll
            for (int L = 0; L < 2; ++L) {
                const int i = tid + (L << 8);
                const int r = i >> 3, cl = i & 7;
                const int cg = (cl ^ (r & 7)) << 3;
                gl2lds16(kb + ((bh << 11) + kn + r) * 64 + cg, &Ks[cur ^ 1][i << 3]);
                gl2lds16(vtb + ((bh << 6) + r) * 2048 + kn + cg, &Vt[cur ^ 1][i << 3]);
            }
            #pragma unroll
            for (int reg = 0; reg < 4; ++reg)
                #pragma unroll
                for (int j = 0; j < 4; ++j)
                    mnext[reg][j] = mbase[(reg << 11) + kn + (j << 4)] * LOG2E;
        }

        // S = Q K^T
        f32x4 sacc[4] = {};
        #pragma unroll
        for (int s = 0; s < 2; ++s) {
            bf16x8 bfr[4];
            #pragma unroll
            for (int j = 0; j < 4; ++j) {
                const int r = (j << 4) + ln;
                bfr[j] = *(const bf16x8*)&Ks[cur][(r << 6) + ((((s << 2) | quad) ^ (r & 7)) << 3)];
            }
            #pragma unroll
            for (int j = 0; j < 4; ++j)
                sacc[j] = __builtin_amdgcn_mfma_f32_16x16x32_bf16(qa[s], bfr[j], sacc[j], 0, 0, 0);
        }

        // p = exp2(s*scale2 + mask*log2e), m==0 fixed shift
        #pragma unroll
        for (int reg = 0; reg < 4; ++reg) {
            const int pr = (quad << 2) + reg;
            #pragma unroll
            for (int j = 0; j < 4; ++j) {
                const float p = exp2f(fmaf(sacc[j][reg], scale2, mcur[reg][j]));
                l_i[reg] += p;
                const int c = (j << 4) + ln;
                Pw[(pr << 6) + (((c >> 3) ^ (pr & 7)) << 3) + (c & 7)] = f2bf(p);
            }
        }

        // O += P V (P wave-private: no barrier between write and read)
        #pragma unroll
        for (int s = 0; s < 2; ++s) {
            const bf16x8 a = *(const bf16x8*)&Pw[(ln << 6) + ((((s << 2) | quad) ^ (ln & 7)) << 3)];
            bf16x8 bfr[4];
            #pragma unroll
            for (int j = 0; j < 4; ++j) {
                const int r = (j << 4) + ln;
                bfr[j] = *(const bf16x8*)&Vt[cur][(r << 6) + ((((s << 2) | quad) ^ (r & 7)) << 3)];
            }
            #pragma unroll
            for (int j = 0; j < 4; ++j)
                O[j] = __builtin_amdgcn_mfma_f32_16x16x32_bf16(a, bfr[j], O[j], 0, 0, 0);
        }

        if (kt < 31) {
            #pragma unroll
            for (int reg = 0; reg < 4; ++reg)
                #pragma unroll
                for (int j = 0; j < 4; ++j)
                    mcur[reg][j] = mnext[reg][j];
        }
    }

    // reduce l over the 16-lane column group, write attn [B,S,H,HD]
    #pragma unroll
    for (int reg = 0; reg < 4; ++reg) {
        float l = l_i[reg];
        l += __shfl_xor(l, 1);
        l += __shfl_xor(l, 2);
        l += __shfl_xor(l, 4);
        l += __shfl_xor(l, 8);
        const float inv = 1.0f / l;
        const int qr = q0 + (wave << 4) + (quad << 2) + reg;
        unsigned short* op = attn + (((size_t)((b_ << 11) + qr)) << 10) + (h << 6);
        #pragma unroll
        for (int j = 0; j < 4; ++j)
            op[(j << 4) + ln] = f2bf(O[j][reg] * inv);
    }
}

// =====================================================================
// Kernel 4: out = attn @ Wo^T + bo, bf16 MFMA, fp32 out.
// =====================================================================
__global__ __launch_bounds__(256, 3) void out_gemm_kernel(
    const unsigned short* __restrict__ X, const unsigned short* __restrict__ W,
    const float* __restrict__ bias, float* __restrict__ out)
{
    __shared__ unsigned short As[128 * 64];
    __shared__ unsigned short Bs[128 * 64];

    const int n0 = blockIdx.x << 7;
    const int m0 = blockIdx.y << 7;
    const int tid = threadIdx.x;
    const int wave = tid >> 6, lane = tid & 63;
    const int quad = lane >> 4, ln = lane & 15;
    const int wm = (wave >> 1) << 6, wn = (wave & 1) << 6;

    f32x4 acc[4][4] = {};

    for (int k0 = 0; k0 < 1024; k0 += 64) {
        #pragma unroll
        for (int L = 0; L < 4; ++L) {
            const int i = tid + (L << 8);
            const int r = i >> 3, cl = i & 7;
            const int cg = (cl ^ (r & 7)) << 3;
            gl2lds16(X + (m0 + r) * 1024 + k0 + cg, &As[i << 3]);
            gl2lds16(W + (n0 + r) * 1024 + k0 + cg, &Bs[i << 3]);
        }
        __syncthreads();
        #pragma unroll
        for (int s = 0; s < 2; ++s) {
            bf16x8 a[4], b[4];
            #pragma unroll
            for (int t = 0; t < 4; ++t) {
                const int ra = wm + (t << 4) + ln;
                a[t] = *(const bf16x8*)&As[(ra << 6) + ((((s << 2) | quad) ^ (ra & 7)) << 3)];
                const int rb = wn + (t << 4) + ln;
                b[t] = *(const bf16x8*)&Bs[(rb << 6) + ((((s << 2) | quad) ^ (rb & 7)) << 3)];
            }
            #pragma unroll
            for (int i = 0; i < 4; ++i)
                #pragma unroll
                for (int j = 0; j < 4; ++j)
                    acc[i][j] = __builtin_amdgcn_mfma_f32_16x16x32_bf16(a[i], b[j], acc[i][j], 0, 0, 0);
        }
        __syncthreads();
    }

    float bv4[4];
    #pragma unroll
    for (int jt = 0; jt < 4; ++jt) bv4[jt] = bias[n0 + wn + (jt << 4) + ln];

    #pragma unroll
    for (int i = 0; i < 4; ++i)
        #pragma unroll
        for (int reg = 0; reg < 4; ++reg) {
            const int m = m0 + wm + (i << 4) + (quad << 2) + reg;
            #pragma unroll
            for (int jt = 0; jt < 4; ++jt) {
                const int n = n0 + wn + (jt << 4) + ln;
                out[m * 1024 + n] = acc[i][jt][reg] + bv4[jt];
            }
        }
}

// =====================================================================
extern "C" void kernel_launch(void* const* d_in, const int* in_sizes, int n_in,
                              void* d_out, int out_size, void* d_ws, size_t ws_size,
                              hipStream_t stream)
{
    const float* hs   = (const float*)d_in[0];
    const float* mask = (const float*)d_in[1];
    const float* Wq   = (const float*)d_in[2];
    const float* bq   = (const float*)d_in[3];
    const float* Wk   = (const float*)d_in[4];
    const float* bk   = (const float*)d_in[5];
    const float* Wv   = (const float*)d_in[6];
    const float* bv   = (const float*)d_in[7];
    const float* Wo   = (const float*)d_in[8];
    const float* bo   = (const float*)d_in[9];

    unsigned short* ws = (unsigned short*)d_ws;
    const size_t M1 = (size_t)1 << 20;
    unsigned short* hsb   = ws;              // 4M
    unsigned short* wall  = ws + 4 * M1;     // wq|wk|wv
    unsigned short* wob   = ws + 7 * M1;
    unsigned short* qbf   = ws + 8 * M1;
    unsigned short* kbf   = ws + 12 * M1;
    unsigned short* vbf   = ws + 16 * M1;
    unsigned short* vtb   = ws + 20 * M1;
    unsigned short* attnb = ws + 24 * M1;

    convert_kernel<<<8192, 256, 0, stream>>>(hs, Wq, Wk, Wv, Wo, ws);
    qkv_gemm_kernel<<<dim3(24, 32), 256, 0, stream>>>(hsb, wall, bq, bk, bv, qbf, kbf, vbf);
    vtrans_kernel<<<1024, 256, 0, stream>>>(vbf, vtb);
    flash_kernel<<<1024, 256, 0, stream>>>(qbf, kbf, vtb, mask, attnb);
    out_gemm_kernel<<<dim3(8, 32), 256, 0, stream>>>(attnb, wob, bo, (float*)d_out);
}

// Round 7
// 242.721 us; speedup vs baseline: 1.6958x; 1.0331x over previous
//
#include <hip/hip_runtime.h>
#include <math.h>

#define S_LEN 2048
#define NHEAD 16
#define HDIM  64

typedef __attribute__((ext_vector_type(8))) short bf16x8;
typedef __attribute__((ext_vector_type(4))) float f32x4;

__device__ __forceinline__ unsigned short f2bf(float f) {
    union { float f; unsigned u; } v; v.f = f;
    unsigned r = v.u + 0x7fffu + ((v.u >> 16) & 1u);
    return (unsigned short)(r >> 16);
}

// async 16B global->LDS. LDS dest must be wave-uniform base + lane*16.
__device__ __forceinline__ void gl2lds16(const void* g, void* l) {
    __builtin_amdgcn_global_load_lds(
        (__attribute__((address_space(1))) void*)(void*)(g),
        (__attribute__((address_space(3))) void*)(l), 16, 0, 0);
}

// =====================================================================
// Kernel 0a: RoPE table: tab[s][i] = {cos, sin}(s * 10000^(-i/32)), i<32.
// =====================================================================
__global__ __launch_bounds__(256) void rope_tab_kernel(float2* __restrict__ tab)
{
    const int gid = blockIdx.x * 256 + threadIdx.x;   // 65536
    const int s = gid >> 5, i = gid & 31;
    const float l2c = 0.41524101186092029f;           // log2(10000)/32
    const float freq = exp2f(-(float)i * l2c);
    const float ang = (float)s * freq;
    float2 cs;
    cs.x = cosf(ang);
    cs.y = sinf(ang);
    tab[gid] = cs;
}

// =====================================================================
// Kernel 0b: fp32 -> bf16 convert. dst: hs[4M] | Wq[1M] | Wk[1M] | Wv[1M] | Wo[1M]
// =====================================================================
__global__ __launch_bounds__(256) void convert_kernel(
    const float* __restrict__ hs, const float* __restrict__ Wq,
    const float* __restrict__ Wk, const float* __restrict__ Wv,
    const float* __restrict__ Wo, unsigned short* __restrict__ dst)
{
    const int gid = blockIdx.x * 256 + threadIdx.x;
    const int n = gid << 2;
    const float* src; int off;
    if (n < (4 << 20))      { src = hs; off = n; }
    else if (n < (5 << 20)) { src = Wq; off = n - (4 << 20); }
    else if (n < (6 << 20)) { src = Wk; off = n - (5 << 20); }
    else if (n < (7 << 20)) { src = Wv; off = n - (6 << 20); }
    else                    { src = Wo; off = n - (7 << 20); }
    const float4 v = *(const float4*)(src + off);
    ushort4 o;
    o.x = f2bf(v.x); o.y = f2bf(v.y); o.z = f2bf(v.z); o.w = f2bf(v.w);
    *(ushort4*)(dst + n) = o;
}

// =====================================================================
// Kernel 1: QKV GEMM, bf16 MFMA 16x16x32, tile 128x128 BK=64, RoPE fused
// via precomputed table (no transcendental in epilogue).
// =====================================================================
__global__ __launch_bounds__(256, 3) void qkv_gemm_kernel(
    const unsigned short* __restrict__ X,     // [4096][1024] bf16
    const unsigned short* __restrict__ Wall,  // wq|wk|wv (1M each)
    const float* __restrict__ bq, const float* __restrict__ bk,
    const float* __restrict__ bv, const float2* __restrict__ rtab,
    unsigned short* __restrict__ qo, unsigned short* __restrict__ ko,
    unsigned short* __restrict__ vo)
{
    __shared__ unsigned short As[128 * 64];
    __shared__ unsigned short Bs[128 * 64];

    const int mat = blockIdx.x >> 3;
    const int n0  = (blockIdx.x & 7) << 7;
    const int m0  = blockIdx.y << 7;
    const unsigned short* W = Wall + (mat << 20);
    const float* bias = (mat == 0) ? bq : (mat == 1) ? bk : bv;
    unsigned short* out = (mat == 0) ? qo : (mat == 1) ? ko : vo;

    const int tid = threadIdx.x;
    const int wave = tid >> 6, lane = tid & 63;
    const int quad = lane >> 4, ln = lane & 15;
    const int wm = (wave >> 1) << 6, wn = (wave & 1) << 6;

    f32x4 acc[4][4] = {};

    for (int k0 = 0; k0 < 1024; k0 += 64) {
        #pragma unroll
        for (int L = 0; L < 4; ++L) {
            const int i = tid + (L << 8);
            const int r = i >> 3, cl = i & 7;
            const int cg = (cl ^ (r & 7)) << 3;
            gl2lds16(X + (m0 + r) * 1024 + k0 + cg, &As[i << 3]);
            gl2lds16(W + (n0 + r) * 1024 + k0 + cg, &Bs[i << 3]);
        }
        __syncthreads();
        #pragma unroll
        for (int s = 0; s < 2; ++s) {
            bf16x8 a[4], b[4];
            #pragma unroll
            for (int t = 0; t < 4; ++t) {
                const int ra = wm + (t << 4) + ln;
                a[t] = *(const bf16x8*)&As[(ra << 6) + ((((s << 2) | quad) ^ (ra & 7)) << 3)];
                const int rb = wn + (t << 4) + ln;
                b[t] = *(const bf16x8*)&Bs[(rb << 6) + ((((s << 2) | quad) ^ (rb & 7)) << 3)];
            }
            #pragma unroll
            for (int i = 0; i < 4; ++i)
                #pragma unroll
                for (int j = 0; j < 4; ++j)
                    acc[i][j] = __builtin_amdgcn_mfma_f32_16x16x32_bf16(a[i], b[j], acc[i][j], 0, 0, 0);
        }
        __syncthreads();
    }

    float bv4[4];
    #pragma unroll
    for (int jt = 0; jt < 4; ++jt) bv4[jt] = bias[n0 + wn + (jt << 4) + ln];

    const int h = (n0 + wn) >> 6;

    #pragma unroll
    for (int i = 0; i < 4; ++i) {
        #pragma unroll
        for (int reg = 0; reg < 4; ++reg) {
            const int m = m0 + wm + (i << 4) + (quad << 2) + reg;
            const int b_ = m >> 11, s_ = m & 2047;
            unsigned short* o = out + ((((b_ << 4) + h) << 11) + s_) * 64;
            if (mat < 2) {
                #pragma unroll
                for (int jl = 0; jl < 2; ++jl) {
                    const int hd = (jl << 4) + ln;     // 0..31
                    const float2 cs = rtab[(s_ << 5) + hd];
                    const float x1 = acc[i][jl][reg] + bv4[jl];
                    const float x2 = acc[i][jl + 2][reg] + bv4[jl + 2];
                    o[hd]      = f2bf(x1 * cs.x - x2 * cs.y);
                    o[hd + 32] = f2bf(x2 * cs.x + x1 * cs.y);
                }
            } else {
                #pragma unroll
                for (int jt = 0; jt < 4; ++jt) {
                    const int hd = (jt << 4) + ln;
                    o[hd] = f2bf(acc[i][jt][reg] + bv4[jt]);
                }
            }
        }
    }
}

// =====================================================================
// Kernel 2: V transpose + k-permute: vt[bh][hd][k0 + idx] = V[k0+per(idx)][hd]
// with per(idx) = 16*(idx&3) + (idx>>2) (inverse of pi(k)=4*(k&15)+(k>>4)).
// Flash's PV MFMA uses the same permuted k-order on the P side, so dot
// products are unchanged.
// =====================================================================
__global__ __launch_bounds__(256) void vtrans_kernel(
    const unsigned short* __restrict__ v, unsigned short* __restrict__ vt)
{
    __shared__ unsigned short T[64][66];
    const int bh = blockIdx.x >> 5;
    const int s0 = (blockIdx.x & 31) << 6;
    const int tid = threadIdx.x;
    #pragma unroll
    for (int L = 0; L < 4; ++L) {
        const int i = tid + (L << 8);
        const int r = i >> 4, c4 = (i & 15) << 2;
        const ushort4 in = *(const ushort4*)(v + ((bh << 11) + s0 + r) * 64 + c4);
        T[r][c4 + 0] = in.x; T[r][c4 + 1] = in.y;
        T[r][c4 + 2] = in.z; T[r][c4 + 3] = in.w;
    }
    __syncthreads();
    #pragma unroll
    for (int L = 0; L < 4; ++L) {
        const int i = tid + (L << 8);
        const int hd = i >> 4, b = i & 15;          // out idx 4b..4b+3
        ushort4 o;
        o.x = T[b][hd];      o.y = T[b + 16][hd];
        o.z = T[b + 32][hd]; o.w = T[b + 48][hd];
        *(ushort4*)(vt + ((bh << 6) + hd) * 2048 + s0 + (b << 2)) = o;
    }
}

// =====================================================================
// Kernel 3: flash v5 — v4 structure, VALU slimmed:
//  * __expf (bare v_exp) instead of ocml exp2f wrapper
//  * P stored in pi-permuted layout: per reg, 4 values contiguous ->
//    round(+0x8000) + 2x v_perm pack + 1x ds_write_b64 (was 16 f2bf +
//    16 ds_write_b16 per iter). V pre-permuted by vtrans to match.
//  Block order idx = bh*32+qt (same-(b,qt) mask tile shares one XCD L2).
// =====================================================================
__global__ __launch_bounds__(256, 4) void flash_kernel(
    const unsigned short* __restrict__ qb, const unsigned short* __restrict__ kb,
    const unsigned short* __restrict__ vtb, const float* __restrict__ mask,
    unsigned short* __restrict__ attn)
{
    __shared__ unsigned short Ks[2][64 * 64];
    __shared__ unsigned short Vt[2][64 * 64];
    __shared__ unsigned short Ps[64 * 64];

    const int qt = blockIdx.x & 31;
    const int bh = blockIdx.x >> 5;
    const int b_ = bh >> 4, h = bh & 15;
    const int q0 = qt << 6;

    const int tid = threadIdx.x;
    const int wave = tid >> 6, lane = tid & 63;
    const int quad = lane >> 4, ln = lane & 15;

    // Q fragments in registers: rows q0+wave*16+ln
    const unsigned short* qrow = qb + ((size_t)((bh << 11) + q0 + (wave << 4) + ln) << 6);
    bf16x8 qa[2];
    qa[0] = *(const bf16x8*)(qrow + (quad << 3));
    qa[1] = *(const bf16x8*)(qrow + 32 + (quad << 3));

    const float scale = 0.125f / logf(2048.0f);

    const float* mbase = mask + ((size_t)b_ << 22)
                       + ((size_t)(q0 + (wave << 4) + (quad << 2)) << 11) + ln;

    unsigned short* Pw = Ps + (wave << 10);

    float l_i[4] = {0.f, 0.f, 0.f, 0.f};
    f32x4 O[4] = {};

    // prologue: stage kt=0 -> buf0, mask[0] -> mcur
    #pragma unroll
    for (int L = 0; L < 2; ++L) {
        const int i = tid + (L << 8);
        const int r = i >> 3, cl = i & 7;
        const int cg = (cl ^ (r & 7)) << 3;
        gl2lds16(kb + ((bh << 11) + r) * 64 + cg, &Ks[0][i << 3]);
        gl2lds16(vtb + ((bh << 6) + r) * 2048 + cg, &Vt[0][i << 3]);
    }
    float mcur[4][4];
    #pragma unroll
    for (int reg = 0; reg < 4; ++reg)
        #pragma unroll
        for (int j = 0; j < 4; ++j)
            mcur[reg][j] = mbase[(reg << 11) + (j << 4)];

    for (int kt = 0; kt < 32; ++kt) {
        const int cur = kt & 1;

        __syncthreads();   // buf[cur] staged; all waves done with buf[cur^1]

        // issue next-iter staging + mask prefetch (completes during compute)
        float mnext[4][4];
        if (kt < 31) {
            const int kn = (kt + 1) << 6;
            #pragma unroll
            for (int L = 0; L < 2; ++L) {
                const int i = tid + (L << 8);
                const int r = i >> 3, cl = i & 7;
                const int cg = (cl ^ (r & 7)) << 3;
                gl2lds16(kb + ((bh << 11) + kn + r) * 64 + cg, &Ks[cur ^ 1][i << 3]);
                gl2lds16(vtb + ((bh << 6) + r) * 2048 + kn + cg, &Vt[cur ^ 1][i << 3]);
            }
            #pragma unroll
            for (int reg = 0; reg < 4; ++reg)
                #pragma unroll
                for (int j = 0; j < 4; ++j)
                    mnext[reg][j] = mbase[(reg << 11) + kn + (j << 4)];
        }

        // S = Q K^T
        f32x4 sacc[4] = {};
        #pragma unroll
        for (int s = 0; s < 2; ++s) {
            bf16x8 bfr[4];
            #pragma unroll
            for (int j = 0; j < 4; ++j) {
                const int r = (j << 4) + ln;
                bfr[j] = *(const bf16x8*)&Ks[cur][(r << 6) + ((((s << 2) | quad) ^ (r & 7)) << 3)];
            }
            #pragma unroll
            for (int j = 0; j < 4; ++j)
                sacc[j] = __builtin_amdgcn_mfma_f32_16x16x32_bf16(qa[s], bfr[j], sacc[j], 0, 0, 0);
        }

        // softmax (m==0 fixed shift) + packed P write in pi-layout:
        // value (reg,j) -> Pl[pr][4*ln + j], 4 contiguous bf16 per reg = b64.
        #pragma unroll
        for (int reg = 0; reg < 4; ++reg) {
            const int pr = (quad << 2) + reg;
            float p[4];
            #pragma unroll
            for (int j = 0; j < 4; ++j) {
                p[j] = __expf(fmaf(sacc[j][reg], scale, mcur[reg][j]));
                l_i[reg] += p[j];
            }
            unsigned u0 = __float_as_uint(p[0]) + 0x8000u;
            unsigned u1 = __float_as_uint(p[1]) + 0x8000u;
            unsigned u2 = __float_as_uint(p[2]) + 0x8000u;
            unsigned u3 = __float_as_uint(p[3]) + 0x8000u;
            uint2 w;
            w.x = __builtin_amdgcn_perm(u1, u0, 0x07060302u);  // [bf(p0),bf(p1)]
            w.y = __builtin_amdgcn_perm(u3, u2, 0x07060302u);  // [bf(p2),bf(p3)]
            const int e = (pr << 6) + ((((ln >> 1) ^ (pr & 7)) << 3)) + ((ln & 1) << 2);
            *(uint2*)&Pw[e] = w;
        }

        // O += P V (both sides in pi-permuted k-order; P wave-private)
        #pragma unroll
        for (int s = 0; s < 2; ++s) {
            const bf16x8 a = *(const bf16x8*)&Pw[(ln << 6) + ((((s << 2) | quad) ^ (ln & 7)) << 3)];
            bf16x8 bfr[4];
            #pragma unroll
            for (int j = 0; j < 4; ++j) {
                const int r = (j << 4) + ln;
                bfr[j] = *(const bf16x8*)&Vt[cur][(r << 6) + ((((s << 2) | quad) ^ (r & 7)) << 3)];
            }
            #pragma unroll
            for (int j = 0; j < 4; ++j)
                O[j] = __builtin_amdgcn_mfma_f32_16x16x32_bf16(a, bfr[j], O[j], 0, 0, 0);
        }

        if (kt < 31) {
            #pragma unroll
            for (int reg = 0; reg < 4; ++reg)
                #pragma unroll
                for (int j = 0; j < 4; ++j)
                    mcur[reg][j] = mnext[reg][j];
        }
    }

    // reduce l over the 16-lane column group, write attn [B,S,H,HD]
    #pragma unroll
    for (int reg = 0; reg < 4; ++reg) {
        float l = l_i[reg];
        l += __shfl_xor(l, 1);
        l += __shfl_xor(l, 2);
        l += __shfl_xor(l, 4);
        l += __shfl_xor(l, 8);
        const float inv = 1.0f / l;
        const int qr = q0 + (wave << 4) + (quad << 2) + reg;
        unsigned short* op = attn + (((size_t)((b_ << 11) + qr)) << 10) + (h << 6);
        #pragma unroll
        for (int j = 0; j < 4; ++j)
            op[(j << 4) + ln] = f2bf(O[j][reg] * inv);
    }
}

// =====================================================================
// Kernel 4: out = attn @ Wo^T + bo, bf16 MFMA, fp32 out.
// =====================================================================
__global__ __launch_bounds__(256, 3) void out_gemm_kernel(
    const unsigned short* __restrict__ X, const unsigned short* __restrict__ W,
    const float* __restrict__ bias, float* __restrict__ out)
{
    __shared__ unsigned short As[128 * 64];
    __shared__ unsigned short Bs[128 * 64];

    const int n0 = blockIdx.x << 7;
    const int m0 = blockIdx.y << 7;
    const int tid = threadIdx.x;
    const int wave = tid >> 6, lane = tid & 63;
    const int quad = lane >> 4, ln = lane & 15;
    const int wm = (wave >> 1) << 6, wn = (wave & 1) << 6;

    f32x4 acc[4][4] = {};

    for (int k0 = 0; k0 < 1024; k0 += 64) {
        #pragma unroll
        for (int L = 0; L < 4; ++L) {
            const int i = tid + (L << 8);
            const int r = i >> 3, cl = i & 7;
            const int cg = (cl ^ (r & 7)) << 3;
            gl2lds16(X + (m0 + r) * 1024 + k0 + cg, &As[i << 3]);
            gl2lds16(W + (n0 + r) * 1024 + k0 + cg, &Bs[i << 3]);
        }
        __syncthreads();
        #pragma unroll
        for (int s = 0; s < 2; ++s) {
            bf16x8 a[4], b[4];
            #pragma unroll
            for (int t = 0; t < 4; ++t) {
                const int ra = wm + (t << 4) + ln;
                a[t] = *(const bf16x8*)&As[(ra << 6) + ((((s << 2) | quad) ^ (ra & 7)) << 3)];
                const int rb = wn + (t << 4) + ln;
                b[t] = *(const bf16x8*)&Bs[(rb << 6) + ((((s << 2) | quad) ^ (rb & 7)) << 3)];
            }
            #pragma unroll
            for (int i = 0; i < 4; ++i)
                #pragma unroll
                for (int j = 0; j < 4; ++j)
                    acc[i][j] = __builtin_amdgcn_mfma_f32_16x16x32_bf16(a[i], b[j], acc[i][j], 0, 0, 0);
        }
        __syncthreads();
    }

    float bv4[4];
    #pragma unroll
    for (int jt = 0; jt < 4; ++jt) bv4[jt] = bias[n0 + wn + (jt << 4) + ln];

    #pragma unroll
    for (int i = 0; i < 4; ++i)
        #pragma unroll
        for (int reg = 0; reg < 4; ++reg) {
            const int m = m0 + wm + (i << 4) + (quad << 2) + reg;
            #pragma unroll
            for (int jt = 0; jt < 4; ++jt) {
                const int n = n0 + wn + (jt << 4) + ln;
                out[m * 1024 + n] = acc[i][jt][reg] + bv4[jt];
            }
        }
}

// =====================================================================
extern "C" void kernel_launch(void* const* d_in, const int* in_sizes, int n_in,
                              void* d_out, int out_size, void* d_ws, size_t ws_size,
                              hipStream_t stream)
{
    const float* hs   = (const float*)d_in[0];
    const float* mask = (const float*)d_in[1];
    const float* Wq   = (const float*)d_in[2];
    const float* bq   = (const float*)d_in[3];
    const float* Wk   = (const float*)d_in[4];
    const float* bk   = (const float*)d_in[5];
    const float* Wv   = (const float*)d_in[6];
    const float* bv   = (const float*)d_in[7];
    const float* Wo   = (const float*)d_in[8];
    const float* bo   = (const float*)d_in[9];

    unsigned short* ws = (unsigned short*)d_ws;
    const size_t M1 = (size_t)1 << 20;
    unsigned short* hsb   = ws;              // 4M
    unsigned short* wall  = ws + 4 * M1;     // wq|wk|wv
    unsigned short* wob   = ws + 7 * M1;
    unsigned short* qbf   = ws + 8 * M1;
    unsigned short* kbf   = ws + 12 * M1;
    unsigned short* vbf   = ws + 16 * M1;
    unsigned short* vtb   = ws + 20 * M1;
    unsigned short* attnb = ws + 24 * M1;
    float2*         rtab  = (float2*)(ws + 28 * M1);   // 512KB

    rope_tab_kernel<<<256, 256, 0, stream>>>(rtab);
    convert_kernel<<<8192, 256, 0, stream>>>(hs, Wq, Wk, Wv, Wo, ws);
    qkv_gemm_kernel<<<dim3(24, 32), 256, 0, stream>>>(hsb, wall, bq, bk, bv, rtab, qbf, kbf, vbf);
    vtrans_kernel<<<1024, 256, 0, stream>>>(vbf, vtb);
    flash_kernel<<<1024, 256, 0, stream>>>(qbf, kbf, vtb, mask, attnb);
    out_gemm_kernel<<<dim3(8, 32), 256, 0, stream>>>(attnb, wob, bo, (float*)d_out);
}

// Round 8
// 237.858 us; speedup vs baseline: 1.7305x; 1.0204x over previous
//
#include <hip/hip_runtime.h>
#include <math.h>

#define S_LEN 2048
#define NHEAD 16
#define HDIM  64

typedef __attribute__((ext_vector_type(8))) short bf16x8;
typedef __attribute__((ext_vector_type(4))) float f32x4;

__device__ __forceinline__ unsigned short f2bf(float f) {
    union { float f; unsigned u; } v; v.f = f;
    unsigned r = v.u + 0x7fffu + ((v.u >> 16) & 1u);
    return (unsigned short)(r >> 16);
}

// async 16B global->LDS. LDS dest must be wave-uniform base + lane*16.
__device__ __forceinline__ void gl2lds16(const void* g, void* l) {
    __builtin_amdgcn_global_load_lds(
        (__attribute__((address_space(1))) void*)(void*)(g),
        (__attribute__((address_space(3))) void*)(l), 16, 0, 0);
}

// =====================================================================
// Kernel 0: fused fp32->bf16 convert (blocks 0..8191) + RoPE table build
// (blocks 8192..8447). dst: hs[4M] | Wq[1M] | Wk[1M] | Wv[1M] | Wo[1M]
// =====================================================================
__global__ __launch_bounds__(256) void convert_kernel(
    const float* __restrict__ hs, const float* __restrict__ Wq,
    const float* __restrict__ Wk, const float* __restrict__ Wv,
    const float* __restrict__ Wo, unsigned short* __restrict__ dst,
    float2* __restrict__ rtab)
{
    const int bid = blockIdx.x;
    if (bid >= 8192) {
        const int gid = (bid - 8192) * 256 + threadIdx.x;   // 65536
        const int s = gid >> 5, i = gid & 31;
        const float l2c = 0.41524101186092029f;             // log2(10000)/32
        const float freq = exp2f(-(float)i * l2c);
        const float ang = (float)s * freq;
        float2 cs;
        cs.x = cosf(ang);
        cs.y = sinf(ang);
        rtab[gid] = cs;
        return;
    }
    const int gid = bid * 256 + threadIdx.x;
    const int n = gid << 2;
    const float* src; int off;
    if (n < (4 << 20))      { src = hs; off = n; }
    else if (n < (5 << 20)) { src = Wq; off = n - (4 << 20); }
    else if (n < (6 << 20)) { src = Wk; off = n - (5 << 20); }
    else if (n < (7 << 20)) { src = Wv; off = n - (6 << 20); }
    else                    { src = Wo; off = n - (7 << 20); }
    const float4 v = *(const float4*)(src + off);
    ushort4 o;
    o.x = f2bf(v.x); o.y = f2bf(v.y); o.z = f2bf(v.z); o.w = f2bf(v.w);
    *(ushort4*)(dst + n) = o;
}

// =====================================================================
// Kernel 1: QKV GEMM, bf16 MFMA 16x16x32, tile 128x128 BK=64, RoPE fused
// via precomputed table.
// =====================================================================
__global__ __launch_bounds__(256, 3) void qkv_gemm_kernel(
    const unsigned short* __restrict__ X,     // [4096][1024] bf16
    const unsigned short* __restrict__ Wall,  // wq|wk|wv (1M each)
    const float* __restrict__ bq, const float* __restrict__ bk,
    const float* __restrict__ bv, const float2* __restrict__ rtab,
    unsigned short* __restrict__ qo, unsigned short* __restrict__ ko,
    unsigned short* __restrict__ vo)
{
    __shared__ unsigned short As[128 * 64];
    __shared__ unsigned short Bs[128 * 64];

    const int mat = blockIdx.x >> 3;
    const int n0  = (blockIdx.x & 7) << 7;
    const int m0  = blockIdx.y << 7;
    const unsigned short* W = Wall + (mat << 20);
    const float* bias = (mat == 0) ? bq : (mat == 1) ? bk : bv;
    unsigned short* out = (mat == 0) ? qo : (mat == 1) ? ko : vo;

    const int tid = threadIdx.x;
    const int wave = tid >> 6, lane = tid & 63;
    const int quad = lane >> 4, ln = lane & 15;
    const int wm = (wave >> 1) << 6, wn = (wave & 1) << 6;

    f32x4 acc[4][4] = {};

    for (int k0 = 0; k0 < 1024; k0 += 64) {
        #pragma unroll
        for (int L = 0; L < 4; ++L) {
            const int i = tid + (L << 8);
            const int r = i >> 3, cl = i & 7;
            const int cg = (cl ^ (r & 7)) << 3;
            gl2lds16(X + (m0 + r) * 1024 + k0 + cg, &As[i << 3]);
            gl2lds16(W + (n0 + r) * 1024 + k0 + cg, &Bs[i << 3]);
        }
        __syncthreads();
        #pragma unroll
        for (int s = 0; s < 2; ++s) {
            bf16x8 a[4], b[4];
            #pragma unroll
            for (int t = 0; t < 4; ++t) {
                const int ra = wm + (t << 4) + ln;
                a[t] = *(const bf16x8*)&As[(ra << 6) + ((((s << 2) | quad) ^ (ra & 7)) << 3)];
                const int rb = wn + (t << 4) + ln;
                b[t] = *(const bf16x8*)&Bs[(rb << 6) + ((((s << 2) | quad) ^ (rb & 7)) << 3)];
            }
            #pragma unroll
            for (int i = 0; i < 4; ++i)
                #pragma unroll
                for (int j = 0; j < 4; ++j)
                    acc[i][j] = __builtin_amdgcn_mfma_f32_16x16x32_bf16(a[i], b[j], acc[i][j], 0, 0, 0);
        }
        __syncthreads();
    }

    float bv4[4];
    #pragma unroll
    for (int jt = 0; jt < 4; ++jt) bv4[jt] = bias[n0 + wn + (jt << 4) + ln];

    const int h = (n0 + wn) >> 6;

    #pragma unroll
    for (int i = 0; i < 4; ++i) {
        #pragma unroll
        for (int reg = 0; reg < 4; ++reg) {
            const int m = m0 + wm + (i << 4) + (quad << 2) + reg;
            const int b_ = m >> 11, s_ = m & 2047;
            unsigned short* o = out + ((((b_ << 4) + h) << 11) + s_) * 64;
            if (mat < 2) {
                #pragma unroll
                for (int jl = 0; jl < 2; ++jl) {
                    const int hd = (jl << 4) + ln;     // 0..31
                    const float2 cs = rtab[(s_ << 5) + hd];
                    const float x1 = acc[i][jl][reg] + bv4[jl];
                    const float x2 = acc[i][jl + 2][reg] + bv4[jl + 2];
                    o[hd]      = f2bf(x1 * cs.x - x2 * cs.y);
                    o[hd + 32] = f2bf(x2 * cs.x + x1 * cs.y);
                }
            } else {
                #pragma unroll
                for (int jt = 0; jt < 4; ++jt) {
                    const int hd = (jt << 4) + ln;
                    o[hd] = f2bf(acc[i][jt][reg] + bv4[jt]);
                }
            }
        }
    }
}

// =====================================================================
// Kernel 2: V transpose [B,H,S,HD] -> [B,H,HD,S], plain (identity k-order;
// the k-permutation now lives on the K staging side of flash).
// =====================================================================
__global__ __launch_bounds__(256) void vtrans_kernel(
    const unsigned short* __restrict__ v, unsigned short* __restrict__ vt)
{
    __shared__ unsigned short T[64][66];
    const int bh = blockIdx.x >> 5;
    const int s0 = (blockIdx.x & 31) << 6;
    const int tid = threadIdx.x;
    #pragma unroll
    for (int L = 0; L < 4; ++L) {
        const int i = tid + (L << 8);
        const int r = i >> 4, c4 = (i & 15) << 2;
        const ushort4 in = *(const ushort4*)(v + ((bh << 11) + s0 + r) * 64 + c4);
        T[r][c4 + 0] = in.x; T[r][c4 + 1] = in.y;
        T[r][c4 + 2] = in.z; T[r][c4 + 3] = in.w;
    }
    __syncthreads();
    #pragma unroll
    for (int L = 0; L < 4; ++L) {
        const int i = tid + (L << 8);
        const int hd = i >> 4, c4 = (i & 15) << 2;
        ushort4 o;
        o.x = T[c4 + 0][hd]; o.y = T[c4 + 1][hd];
        o.z = T[c4 + 2][hd]; o.w = T[c4 + 3][hd];
        *(ushort4*)(vt + ((bh << 6) + hd) * 2048 + s0 + c4) = o;
    }
}

// =====================================================================
// Kernel 3: flash v6 — K rows staged pi-permuted so S-col (j,ln) is
// original k = 4*ln+j:
//   * mask loads become ONE float4 per reg (was 4 dwords) — 4 VMEM/iter
//   * P packed write (uint2) is in identity k-order -> plain Vt works
//   * staging global addresses hoisted out of the k-loop
//  Block order idx = bh*32+qt (same-(b,qt) mask tile shares one XCD L2;
//  R4 proved bh-low-bit order costs 5x FETCH).
// =====================================================================
__global__ __launch_bounds__(256, 4) void flash_kernel(
    const unsigned short* __restrict__ qb, const unsigned short* __restrict__ kb,
    const unsigned short* __restrict__ vtb, const float* __restrict__ mask,
    unsigned short* __restrict__ attn)
{
    __shared__ unsigned short Ks[2][64 * 64];
    __shared__ unsigned short Vt[2][64 * 64];
    __shared__ unsigned short Ps[64 * 64];

    const int qt = blockIdx.x & 31;
    const int bh = blockIdx.x >> 5;
    const int b_ = bh >> 4, h = bh & 15;
    const int q0 = qt << 6;

    const int tid = threadIdx.x;
    const int wave = tid >> 6, lane = tid & 63;
    const int quad = lane >> 4, ln = lane & 15;

    // Q fragments in registers: rows q0+wave*16+ln
    const unsigned short* qrow = qb + ((size_t)((bh << 11) + q0 + (wave << 4) + ln) << 6);
    bf16x8 qa[2];
    qa[0] = *(const bf16x8*)(qrow + (quad << 3));
    qa[1] = *(const bf16x8*)(qrow + 32 + (quad << 3));

    const float scale = 0.125f / logf(2048.0f);

    // mask: contiguous float4 per row (k = 4*ln .. 4*ln+3 in orig order)
    const float* mbase = mask + ((size_t)b_ << 22)
                       + ((size_t)(q0 + (wave << 4) + (quad << 2)) << 11) + (ln << 2);

    unsigned short* Pw = Ps + (wave << 10);

    // per-thread staging bases (hoisted): thread covers LDS halves L=0,1
    const int i0 = tid, i1 = tid + 256;
    const int r0 = i0 >> 3, c0 = ((i0 & 7) ^ (r0 & 7)) << 3;
    const int r1 = i1 >> 3, c1 = ((i1 & 7) ^ (r1 & 7)) << 3;
    const int p0 = ((r0 & 15) << 2) + (r0 >> 4);   // pi(r): K global row
    const int p1 = ((r1 & 15) << 2) + (r1 >> 4);
    const unsigned short* kg0 = kb + ((bh << 11) + p0) * 64 + c0;
    const unsigned short* kg1 = kb + ((bh << 11) + p1) * 64 + c1;
    const unsigned short* vg0 = vtb + ((bh << 6) + r0) * 2048 + c0;
    const unsigned short* vg1 = vtb + ((bh << 6) + r1) * 2048 + c1;

    float l_i[4] = {0.f, 0.f, 0.f, 0.f};
    f32x4 O[4] = {};

    // prologue: stage kt=0 -> buf0, mask[0] -> mcur
    gl2lds16(kg0, &Ks[0][i0 << 3]);
    gl2lds16(kg1, &Ks[0][i1 << 3]);
    gl2lds16(vg0, &Vt[0][i0 << 3]);
    gl2lds16(vg1, &Vt[0][i1 << 3]);
    float4 mcur[4];
    #pragma unroll
    for (int reg = 0; reg < 4; ++reg)
        mcur[reg] = *(const float4*)(mbase + (reg << 11));

    for (int kt = 0; kt < 32; ++kt) {
        const int cur = kt & 1;

        __syncthreads();   // buf[cur] staged; all waves done with buf[cur^1]

        // issue next-iter staging + mask prefetch (completes during compute)
        float4 mnext[4];
        if (kt < 31) {
            const int kn = (kt + 1) << 6;
            gl2lds16(kg0 + (kn << 6), &Ks[cur ^ 1][i0 << 3]);
            gl2lds16(kg1 + (kn << 6), &Ks[cur ^ 1][i1 << 3]);
            gl2lds16(vg0 + kn, &Vt[cur ^ 1][i0 << 3]);
            gl2lds16(vg1 + kn, &Vt[cur ^ 1][i1 << 3]);
            #pragma unroll
            for (int reg = 0; reg < 4; ++reg)
                mnext[reg] = *(const float4*)(mbase + kn + (reg << 11));
        }

        // S = Q K^T (K rows pi-permuted: S col (j,ln) == orig k 4*ln+j)
        f32x4 sacc[4] = {};
        #pragma unroll
        for (int s = 0; s < 2; ++s) {
            bf16x8 bfr[4];
            #pragma unroll
            for (int j = 0; j < 4; ++j) {
                const int r = (j << 4) + ln;
                bfr[j] = *(const bf16x8*)&Ks[cur][(r << 6) + ((((s << 2) | quad) ^ (r & 7)) << 3)];
            }
            #pragma unroll
            for (int j = 0; j < 4; ++j)
                sacc[j] = __builtin_amdgcn_mfma_f32_16x16x32_bf16(qa[s], bfr[j], sacc[j], 0, 0, 0);
        }

        // softmax (m==0 fixed shift) + packed P write, identity k-order:
        // value (reg,j) -> Pw[pr][4*ln + j], 4 contiguous bf16 = one b64.
        #pragma unroll
        for (int reg = 0; reg < 4; ++reg) {
            const int pr = (quad << 2) + reg;
            const float m0f = mcur[reg].x, m1f = mcur[reg].y,
                        m2f = mcur[reg].z, m3f = mcur[reg].w;
            float p[4];
            p[0] = __expf(fmaf(sacc[0][reg], scale, m0f));
            p[1] = __expf(fmaf(sacc[1][reg], scale, m1f));
            p[2] = __expf(fmaf(sacc[2][reg], scale, m2f));
            p[3] = __expf(fmaf(sacc[3][reg], scale, m3f));
            l_i[reg] += (p[0] + p[1]) + (p[2] + p[3]);
            unsigned u0 = __float_as_uint(p[0]) + 0x8000u;
            unsigned u1 = __float_as_uint(p[1]) + 0x8000u;
            unsigned u2 = __float_as_uint(p[2]) + 0x8000u;
            unsigned u3 = __float_as_uint(p[3]) + 0x8000u;
            uint2 w;
            w.x = __builtin_amdgcn_perm(u1, u0, 0x07060302u);
            w.y = __builtin_amdgcn_perm(u3, u2, 0x07060302u);
            const int e = (pr << 6) + ((((ln >> 1) ^ (pr & 7)) << 3)) + ((ln & 1) << 2);
            *(uint2*)&Pw[e] = w;
        }

        // O += P V (identity k-order both sides; P wave-private)
        #pragma unroll
        for (int s = 0; s < 2; ++s) {
            const bf16x8 a = *(const bf16x8*)&Pw[(ln << 6) + ((((s << 2) | quad) ^ (ln & 7)) << 3)];
            bf16x8 bfr[4];
            #pragma unroll
            for (int j = 0; j < 4; ++j) {
                const int r = (j << 4) + ln;
                bfr[j] = *(const bf16x8*)&Vt[cur][(r << 6) + ((((s << 2) | quad) ^ (r & 7)) << 3)];
            }
            #pragma unroll
            for (int j = 0; j < 4; ++j)
                O[j] = __builtin_amdgcn_mfma_f32_16x16x32_bf16(a, bfr[j], O[j], 0, 0, 0);
        }

        if (kt < 31) {
            #pragma unroll
            for (int reg = 0; reg < 4; ++reg)
                mcur[reg] = mnext[reg];
        }
    }

    // reduce l over the 16-lane column group, write attn [B,S,H,HD]
    #pragma unroll
    for (int reg = 0; reg < 4; ++reg) {
        float l = l_i[reg];
        l += __shfl_xor(l, 1);
        l += __shfl_xor(l, 2);
        l += __shfl_xor(l, 4);
        l += __shfl_xor(l, 8);
        const float inv = 1.0f / l;
        const int qr = q0 + (wave << 4) + (quad << 2) + reg;
        unsigned short* op = attn + (((size_t)((b_ << 11) + qr)) << 10) + (h << 6);
        #pragma unroll
        for (int j = 0; j < 4; ++j)
            op[(j << 4) + ln] = f2bf(O[j][reg] * inv);
    }
}

// =====================================================================
// Kernel 4: out = attn @ Wo^T + bo, bf16 MFMA, fp32 out.
// =====================================================================
__global__ __launch_bounds__(256, 3) void out_gemm_kernel(
    const unsigned short* __restrict__ X, const unsigned short* __restrict__ W,
    const float* __restrict__ bias, float* __restrict__ out)
{
    __shared__ unsigned short As[128 * 64];
    __shared__ unsigned short Bs[128 * 64];

    const int n0 = blockIdx.x << 7;
    const int m0 = blockIdx.y << 7;
    const int tid = threadIdx.x;
    const int wave = tid >> 6, lane = tid & 63;
    const int quad = lane >> 4, ln = lane & 15;
    const int wm = (wave >> 1) << 6, wn = (wave & 1) << 6;

    f32x4 acc[4][4] = {};

    for (int k0 = 0; k0 < 1024; k0 += 64) {
        #pragma unroll
        for (int L = 0; L < 4; ++L) {
            const int i = tid + (L << 8);
            const int r = i >> 3, cl = i & 7;
            const int cg = (cl ^ (r & 7)) << 3;
            gl2lds16(X + (m0 + r) * 1024 + k0 + cg, &As[i << 3]);
            gl2lds16(W + (n0 + r) * 1024 + k0 + cg, &Bs[i << 3]);
        }
        __syncthreads();
        #pragma unroll
        for (int s = 0; s < 2; ++s) {
            bf16x8 a[4], b[4];
            #pragma unroll
            for (int t = 0; t < 4; ++t) {
                const int ra = wm + (t << 4) + ln;
                a[t] = *(const bf16x8*)&As[(ra << 6) + ((((s << 2) | quad) ^ (ra & 7)) << 3)];
                const int rb = wn + (t << 4) + ln;
                b[t] = *(const bf16x8*)&Bs[(rb << 6) + ((((s << 2) | quad) ^ (rb & 7)) << 3)];
            }
            #pragma unroll
            for (int i = 0; i < 4; ++i)
                #pragma unroll
                for (int j = 0; j < 4; ++j)
                    acc[i][j] = __builtin_amdgcn_mfma_f32_16x16x32_bf16(a[i], b[j], acc[i][j], 0, 0, 0);
        }
        __syncthreads();
    }

    float bv4[4];
    #pragma unroll
    for (int jt = 0; jt < 4; ++jt) bv4[jt] = bias[n0 + wn + (jt << 4) + ln];

    #pragma unroll
    for (int i = 0; i < 4; ++i)
        #pragma unroll
        for (int reg = 0; reg < 4; ++reg) {
            const int m = m0 + wm + (i << 4) + (quad << 2) + reg;
            #pragma unroll
            for (int jt = 0; jt < 4; ++jt) {
                const int n = n0 + wn + (jt << 4) + ln;
                out[m * 1024 + n] = acc[i][jt][reg] + bv4[jt];
            }
        }
}

// =====================================================================
extern "C" void kernel_launch(void* const* d_in, const int* in_sizes, int n_in,
                              void* d_out, int out_size, void* d_ws, size_t ws_size,
                              hipStream_t stream)
{
    const float* hs   = (const float*)d_in[0];
    const float* mask = (const float*)d_in[1];
    const float* Wq   = (const float*)d_in[2];
    const float* bq   = (const float*)d_in[3];
    const float* Wk   = (const float*)d_in[4];
    const float* bk   = (const float*)d_in[5];
    const float* Wv   = (const float*)d_in[6];
    const float* bv   = (const float*)d_in[7];
    const float* Wo   = (const float*)d_in[8];
    const float* bo   = (const float*)d_in[9];

    unsigned short* ws = (unsigned short*)d_ws;
    const size_t M1 = (size_t)1 << 20;
    unsigned short* hsb   = ws;              // 4M
    unsigned short* wall  = ws + 4 * M1;     // wq|wk|wv
    unsigned short* wob   = ws + 7 * M1;
    unsigned short* qbf   = ws + 8 * M1;
    unsigned short* kbf   = ws + 12 * M1;
    unsigned short* vbf   = ws + 16 * M1;
    unsigned short* vtb   = ws + 20 * M1;
    unsigned short* attnb = ws + 24 * M1;
    float2*         rtab  = (float2*)(ws + 28 * M1);   // 512KB

    convert_kernel<<<8448, 256, 0, stream>>>(hs, Wq, Wk, Wv, Wo, ws, rtab);
    qkv_gemm_kernel<<<dim3(24, 32), 256, 0, stream>>>(hsb, wall, bq, bk, bv, rtab, qbf, kbf, vbf);
    vtrans_kernel<<<1024, 256, 0, stream>>>(vbf, vtb);
    flash_kernel<<<1024, 256, 0, stream>>>(qbf, kbf, vtb, mask, attnb);
    out_gemm_kernel<<<dim3(8, 32), 256, 0, stream>>>(attnb, wob, bo, (float*)d_out);
}

// Round 9
// 225.161 us; speedup vs baseline: 1.8281x; 1.0564x over previous
//
#include <hip/hip_runtime.h>
#include <math.h>

#define S_LEN 2048
#define NHEAD 16
#define HDIM  64

typedef __attribute__((ext_vector_type(8))) short bf16x8;
typedef __attribute__((ext_vector_type(4))) float f32x4;

__device__ __forceinline__ unsigned short f2bf(float f) {
    union { float f; unsigned u; } v; v.f = f;
    unsigned r = v.u + 0x7fffu + ((v.u >> 16) & 1u);
    return (unsigned short)(r >> 16);
}

// async 16B global->LDS. LDS dest must be wave-uniform base + lane*16.
__device__ __forceinline__ void gl2lds16(const void* g, void* l) {
    __builtin_amdgcn_global_load_lds(
        (__attribute__((address_space(1))) void*)(void*)(g),
        (__attribute__((address_space(3))) void*)(l), 16, 0, 0);
}

// =====================================================================
// Kernel 0: fused fp32->bf16 convert (blocks 0..8191) + RoPE table build
// (blocks 8192..8447). dst: hs[4M] | Wq[1M] | Wk[1M] | Wv[1M] | Wo[1M]
// =====================================================================
__global__ __launch_bounds__(256) void convert_kernel(
    const float* __restrict__ hs, const float* __restrict__ Wq,
    const float* __restrict__ Wk, const float* __restrict__ Wv,
    const float* __restrict__ Wo, unsigned short* __restrict__ dst,
    float2* __restrict__ rtab)
{
    const int bid = blockIdx.x;
    if (bid >= 8192) {
        const int gid = (bid - 8192) * 256 + threadIdx.x;   // 65536
        const int s = gid >> 5, i = gid & 31;
        const float l2c = 0.41524101186092029f;             // log2(10000)/32
        const float freq = exp2f(-(float)i * l2c);
        const float ang = (float)s * freq;
        float2 cs;
        cs.x = cosf(ang);
        cs.y = sinf(ang);
        rtab[gid] = cs;
        return;
    }
    const int gid = bid * 256 + threadIdx.x;
    const int n = gid << 2;
    const float* src; int off;
    if (n < (4 << 20))      { src = hs; off = n; }
    else if (n < (5 << 20)) { src = Wq; off = n - (4 << 20); }
    else if (n < (6 << 20)) { src = Wk; off = n - (5 << 20); }
    else if (n < (7 << 20)) { src = Wv; off = n - (6 << 20); }
    else                    { src = Wo; off = n - (7 << 20); }
    const float4 v = *(const float4*)(src + off);
    ushort4 o;
    o.x = f2bf(v.x); o.y = f2bf(v.y); o.z = f2bf(v.z); o.w = f2bf(v.w);
    *(ushort4*)(dst + n) = o;
}

// =====================================================================
// Kernel 1: QKV GEMM, bf16 MFMA 16x16x32, tile 128x128 BK=64, RoPE fused.
// B-rows staged PERMUTED (tau) so each lane's 4 output columns pack:
//   Q/K: tau(r) = 2*ln + (jt&1) + 32*(jt>>1)  -> lane holds {n,n+1,n+32,n+33}
//        RoPE pairs in-lane, 1 float4 rtab load, 2x b32 stores
//   V:   tau(r) = 4*ln + jt                   -> 1x b64 store, float4 bias
// Output layouts stay IDENTITY -> zero downstream changes.
// =====================================================================
__global__ __launch_bounds__(256, 3) void qkv_gemm_kernel(
    const unsigned short* __restrict__ X,     // [4096][1024] bf16
    const unsigned short* __restrict__ Wall,  // wq|wk|wv (1M each)
    const float* __restrict__ bq, const float* __restrict__ bk,
    const float* __restrict__ bv, const float2* __restrict__ rtab,
    unsigned short* __restrict__ qo, unsigned short* __restrict__ ko,
    unsigned short* __restrict__ vo)
{
    __shared__ unsigned short As[128 * 64];
    __shared__ unsigned short Bs[128 * 64];

    const int mat = blockIdx.x >> 3;
    const int n0  = (blockIdx.x & 7) << 7;
    const int m0  = blockIdx.y << 7;
    const unsigned short* W = Wall + (mat << 20);
    const float* bias = (mat == 0) ? bq : (mat == 1) ? bk : bv;
    unsigned short* out = (mat == 0) ? qo : (mat == 1) ? ko : vo;

    const int tid = threadIdx.x;
    const int wave = tid >> 6, lane = tid & 63;
    const int quad = lane >> 4, ln = lane & 15;
    const int wm = (wave >> 1) << 6, wn = (wave & 1) << 6;

    // hoisted staging pointers (tau row-permutation on B)
    const unsigned short* xptr[4];
    const unsigned short* wptr[4];
    #pragma unroll
    for (int L = 0; L < 4; ++L) {
        const int i = tid + (L << 8);
        const int r = i >> 3, cl = i & 7;
        const int cg = (cl ^ (r & 7)) << 3;
        const int rq = r & 63;
        const int tau = (mat < 2)
            ? ((r & 64) | ((rq & 15) << 1) | ((rq >> 4) & 1) | (((rq >> 5) & 1) << 5))
            : ((r & 64) | ((rq & 15) << 2) | (rq >> 4));
        xptr[L] = X + (m0 + r) * 1024 + cg;
        wptr[L] = W + (n0 + tau) * 1024 + cg;
    }

    f32x4 acc[4][4] = {};

    for (int k0 = 0; k0 < 1024; k0 += 64) {
        #pragma unroll
        for (int L = 0; L < 4; ++L) {
            const int i = tid + (L << 8);
            gl2lds16(xptr[L] + k0, &As[i << 3]);
            gl2lds16(wptr[L] + k0, &Bs[i << 3]);
        }
        __syncthreads();
        #pragma unroll
        for (int s = 0; s < 2; ++s) {
            bf16x8 a[4], b[4];
            #pragma unroll
            for (int t = 0; t < 4; ++t) {
                const int ra = wm + (t << 4) + ln;
                a[t] = *(const bf16x8*)&As[(ra << 6) + ((((s << 2) | quad) ^ (ra & 7)) << 3)];
                const int rb = wn + (t << 4) + ln;
                b[t] = *(const bf16x8*)&Bs[(rb << 6) + ((((s << 2) | quad) ^ (rb & 7)) << 3)];
            }
            #pragma unroll
            for (int i = 0; i < 4; ++i)
                #pragma unroll
                for (int j = 0; j < 4; ++j)
                    acc[i][j] = __builtin_amdgcn_mfma_f32_16x16x32_bf16(a[i], b[j], acc[i][j], 0, 0, 0);
        }
        __syncthreads();
    }

    const int h = (n0 + wn) >> 6;

    if (mat < 2) {
        const int nb = n0 + wn + (ln << 1);
        const float b0 = bias[nb],      b1 = bias[nb + 1];
        const float b2 = bias[nb + 32], b3 = bias[nb + 33];
        #pragma unroll
        for (int i = 0; i < 4; ++i) {
            #pragma unroll
            for (int reg = 0; reg < 4; ++reg) {
                const int m = m0 + wm + (i << 4) + (quad << 2) + reg;
                const int b_ = m >> 11, s_ = m & 2047;
                unsigned short* o = out + ((((b_ << 4) + h) << 11) + s_) * 64;
                const float4 cs = *(const float4*)(rtab + (s_ << 5) + (ln << 1));
                const float x1a = acc[i][0][reg] + b0, x1b = acc[i][1][reg] + b1;
                const float x2a = acc[i][2][reg] + b2, x2b = acc[i][3][reg] + b3;
                const float r0a = x1a * cs.x - x2a * cs.y;
                const float r0b = x1b * cs.z - x2b * cs.w;
                const float r1a = x2a * cs.x + x1a * cs.y;
                const float r1b = x2b * cs.z + x1b * cs.w;
                const unsigned ua = __float_as_uint(r0a) + 0x8000u;
                const unsigned ub = __float_as_uint(r0b) + 0x8000u;
                const unsigned uc = __float_as_uint(r1a) + 0x8000u;
                const unsigned ud = __float_as_uint(r1b) + 0x8000u;
                *(unsigned*)(o + (ln << 1))      = __builtin_amdgcn_perm(ub, ua, 0x07060302u);
                *(unsigned*)(o + 32 + (ln << 1)) = __builtin_amdgcn_perm(ud, uc, 0x07060302u);
            }
        }
    } else {
        const float4 bv4 = *(const float4*)(bias + n0 + wn + (ln << 2));
        #pragma unroll
        for (int i = 0; i < 4; ++i)
            #pragma unroll
            for (int reg = 0; reg < 4; ++reg) {
                const int m = m0 + wm + (i << 4) + (quad << 2) + reg;
                const int b_ = m >> 11, s_ = m & 2047;
                unsigned short* o = out + ((((b_ << 4) + h) << 11) + s_) * 64;
                const unsigned ua = __float_as_uint(acc[i][0][reg] + bv4.x) + 0x8000u;
                const unsigned ub = __float_as_uint(acc[i][1][reg] + bv4.y) + 0x8000u;
                const unsigned uc = __float_as_uint(acc[i][2][reg] + bv4.z) + 0x8000u;
                const unsigned ud = __float_as_uint(acc[i][3][reg] + bv4.w) + 0x8000u;
                uint2 w;
                w.x = __builtin_amdgcn_perm(ub, ua, 0x07060302u);
                w.y = __builtin_amdgcn_perm(ud, uc, 0x07060302u);
                *(uint2*)(o + (ln << 2)) = w;
            }
    }
}

// =====================================================================
// Kernel 2: V transpose [B,H,S,HD] -> [B,H,HD,S] (identity layouts).
// =====================================================================
__global__ __launch_bounds__(256) void vtrans_kernel(
    const unsigned short* __restrict__ v, unsigned short* __restrict__ vt)
{
    __shared__ unsigned short T[64][66];
    const int bh = blockIdx.x >> 5;
    const int s0 = (blockIdx.x & 31) << 6;
    const int tid = threadIdx.x;
    #pragma unroll
    for (int L = 0; L < 4; ++L) {
        const int i = tid + (L << 8);
        const int r = i >> 4, c4 = (i & 15) << 2;
        const ushort4 in = *(const ushort4*)(v + ((bh << 11) + s0 + r) * 64 + c4);
        T[r][c4 + 0] = in.x; T[r][c4 + 1] = in.y;
        T[r][c4 + 2] = in.z; T[r][c4 + 3] = in.w;
    }
    __syncthreads();
    #pragma unroll
    for (int L = 0; L < 4; ++L) {
        const int i = tid + (L << 8);
        const int hd = i >> 4, c4 = (i & 15) << 2;
        ushort4 o;
        o.x = T[c4 + 0][hd]; o.y = T[c4 + 1][hd];
        o.z = T[c4 + 2][hd]; o.w = T[c4 + 3][hd];
        *(ushort4*)(vt + ((bh << 6) + hd) * 2048 + s0 + c4) = o;
    }
}

// =====================================================================
// Kernel 3: flash v6 (unchanged from R7) — K rows staged pi-permuted so
// S-col (j,ln) is original k = 4*ln+j: float4 mask loads, packed P write,
// hoisted staging bases, dbuf K/V, m==0 softmax.
// Block order idx = bh*32+qt (mask-tile XCD locality; R4 proved the
// alternative costs 5x FETCH).
// =====================================================================
__global__ __launch_bounds__(256, 4) void flash_kernel(
    const unsigned short* __restrict__ qb, const unsigned short* __restrict__ kb,
    const unsigned short* __restrict__ vtb, const float* __restrict__ mask,
    unsigned short* __restrict__ attn)
{
    __shared__ unsigned short Ks[2][64 * 64];
    __shared__ unsigned short Vt[2][64 * 64];
    __shared__ unsigned short Ps[64 * 64];

    const int qt = blockIdx.x & 31;
    const int bh = blockIdx.x >> 5;
    const int b_ = bh >> 4, h = bh & 15;
    const int q0 = qt << 6;

    const int tid = threadIdx.x;
    const int wave = tid >> 6, lane = tid & 63;
    const int quad = lane >> 4, ln = lane & 15;

    const unsigned short* qrow = qb + ((size_t)((bh << 11) + q0 + (wave << 4) + ln) << 6);
    bf16x8 qa[2];
    qa[0] = *(const bf16x8*)(qrow + (quad << 3));
    qa[1] = *(const bf16x8*)(qrow + 32 + (quad << 3));

    const float scale = 0.125f / logf(2048.0f);

    const float* mbase = mask + ((size_t)b_ << 22)
                       + ((size_t)(q0 + (wave << 4) + (quad << 2)) << 11) + (ln << 2);

    unsigned short* Pw = Ps + (wave << 10);

    const int i0 = tid, i1 = tid + 256;
    const int r0 = i0 >> 3, c0 = ((i0 & 7) ^ (r0 & 7)) << 3;
    const int r1 = i1 >> 3, c1 = ((i1 & 7) ^ (r1 & 7)) << 3;
    const int p0 = ((r0 & 15) << 2) + (r0 >> 4);
    const int p1 = ((r1 & 15) << 2) + (r1 >> 4);
    const unsigned short* kg0 = kb + ((bh << 11) + p0) * 64 + c0;
    const unsigned short* kg1 = kb + ((bh << 11) + p1) * 64 + c1;
    const unsigned short* vg0 = vtb + ((bh << 6) + r0) * 2048 + c0;
    const unsigned short* vg1 = vtb + ((bh << 6) + r1) * 2048 + c1;

    float l_i[4] = {0.f, 0.f, 0.f, 0.f};
    f32x4 O[4] = {};

    gl2lds16(kg0, &Ks[0][i0 << 3]);
    gl2lds16(kg1, &Ks[0][i1 << 3]);
    gl2lds16(vg0, &Vt[0][i0 << 3]);
    gl2lds16(vg1, &Vt[0][i1 << 3]);
    float4 mcur[4];
    #pragma unroll
    for (int reg = 0; reg < 4; ++reg)
        mcur[reg] = *(const float4*)(mbase + (reg << 11));

    for (int kt = 0; kt < 32; ++kt) {
        const int cur = kt & 1;

        __syncthreads();

        float4 mnext[4];
        if (kt < 31) {
            const int kn = (kt + 1) << 6;
            gl2lds16(kg0 + (kn << 6), &Ks[cur ^ 1][i0 << 3]);
            gl2lds16(kg1 + (kn << 6), &Ks[cur ^ 1][i1 << 3]);
            gl2lds16(vg0 + kn, &Vt[cur ^ 1][i0 << 3]);
            gl2lds16(vg1 + kn, &Vt[cur ^ 1][i1 << 3]);
            #pragma unroll
            for (int reg = 0; reg < 4; ++reg)
                mnext[reg] = *(const float4*)(mbase + kn + (reg << 11));
        }

        f32x4 sacc[4] = {};
        #pragma unroll
        for (int s = 0; s < 2; ++s) {
            bf16x8 bfr[4];
            #pragma unroll
            for (int j = 0; j < 4; ++j) {
                const int r = (j << 4) + ln;
                bfr[j] = *(const bf16x8*)&Ks[cur][(r << 6) + ((((s << 2) | quad) ^ (r & 7)) << 3)];
            }
            #pragma unroll
            for (int j = 0; j < 4; ++j)
                sacc[j] = __builtin_amdgcn_mfma_f32_16x16x32_bf16(qa[s], bfr[j], sacc[j], 0, 0, 0);
        }

        #pragma unroll
        for (int reg = 0; reg < 4; ++reg) {
            const int pr = (quad << 2) + reg;
            const float m0f = mcur[reg].x, m1f = mcur[reg].y,
                        m2f = mcur[reg].z, m3f = mcur[reg].w;
            float p[4];
            p[0] = __expf(fmaf(sacc[0][reg], scale, m0f));
            p[1] = __expf(fmaf(sacc[1][reg], scale, m1f));
            p[2] = __expf(fmaf(sacc[2][reg], scale, m2f));
            p[3] = __expf(fmaf(sacc[3][reg], scale, m3f));
            l_i[reg] += (p[0] + p[1]) + (p[2] + p[3]);
            unsigned u0 = __float_as_uint(p[0]) + 0x8000u;
            unsigned u1 = __float_as_uint(p[1]) + 0x8000u;
            unsigned u2 = __float_as_uint(p[2]) + 0x8000u;
            unsigned u3 = __float_as_uint(p[3]) + 0x8000u;
            uint2 w;
            w.x = __builtin_amdgcn_perm(u1, u0, 0x07060302u);
            w.y = __builtin_amdgcn_perm(u3, u2, 0x07060302u);
            const int e = (pr << 6) + ((((ln >> 1) ^ (pr & 7)) << 3)) + ((ln & 1) << 2);
            *(uint2*)&Pw[e] = w;
        }

        #pragma unroll
        for (int s = 0; s < 2; ++s) {
            const bf16x8 a = *(const bf16x8*)&Pw[(ln << 6) + ((((s << 2) | quad) ^ (ln & 7)) << 3)];
            bf16x8 bfr[4];
            #pragma unroll
            for (int j = 0; j < 4; ++j) {
                const int r = (j << 4) + ln;
                bfr[j] = *(const bf16x8*)&Vt[cur][(r << 6) + ((((s << 2) | quad) ^ (r & 7)) << 3)];
            }
            #pragma unroll
            for (int j = 0; j < 4; ++j)
                O[j] = __builtin_amdgcn_mfma_f32_16x16x32_bf16(a, bfr[j], O[j], 0, 0, 0);
        }

        if (kt < 31) {
            #pragma unroll
            for (int reg = 0; reg < 4; ++reg)
                mcur[reg] = mnext[reg];
        }
    }

    #pragma unroll
    for (int reg = 0; reg < 4; ++reg) {
        float l = l_i[reg];
        l += __shfl_xor(l, 1);
        l += __shfl_xor(l, 2);
        l += __shfl_xor(l, 4);
        l += __shfl_xor(l, 8);
        const float inv = 1.0f / l;
        const int qr = q0 + (wave << 4) + (quad << 2) + reg;
        unsigned short* op = attn + (((size_t)((b_ << 11) + qr)) << 10) + (h << 6);
        #pragma unroll
        for (int j = 0; j < 4; ++j)
            op[(j << 4) + ln] = f2bf(O[j][reg] * inv);
    }
}

// =====================================================================
// Kernel 4: out = attn @ Wo^T + bo, bf16 MFMA, fp32 out.
// tau-permuted Wo row staging -> lane's 4 columns contiguous -> float4
// stores + float4 bias. Output layout identity.
// =====================================================================
__global__ __launch_bounds__(256, 3) void out_gemm_kernel(
    const unsigned short* __restrict__ X, const unsigned short* __restrict__ W,
    const float* __restrict__ bias, float* __restrict__ out)
{
    __shared__ unsigned short As[128 * 64];
    __shared__ unsigned short Bs[128 * 64];

    const int n0 = blockIdx.x << 7;
    const int m0 = blockIdx.y << 7;
    const int tid = threadIdx.x;
    const int wave = tid >> 6, lane = tid & 63;
    const int quad = lane >> 4, ln = lane & 15;
    const int wm = (wave >> 1) << 6, wn = (wave & 1) << 6;

    const unsigned short* xptr[4];
    const unsigned short* wptr[4];
    #pragma unroll
    for (int L = 0; L < 4; ++L) {
        const int i = tid + (L << 8);
        const int r = i >> 3, cl = i & 7;
        const int cg = (cl ^ (r & 7)) << 3;
        const int rq = r & 63;
        const int tau = (r & 64) | ((rq & 15) << 2) | (rq >> 4);
        xptr[L] = X + (m0 + r) * 1024 + cg;
        wptr[L] = W + (n0 + tau) * 1024 + cg;
    }

    f32x4 acc[4][4] = {};

    for (int k0 = 0; k0 < 1024; k0 += 64) {
        #pragma unroll
        for (int L = 0; L < 4; ++L) {
            const int i = tid + (L << 8);
            gl2lds16(xptr[L] + k0, &As[i << 3]);
            gl2lds16(wptr[L] + k0, &Bs[i << 3]);
        }
        __syncthreads();
        #pragma unroll
        for (int s = 0; s < 2; ++s) {
            bf16x8 a[4], b[4];
            #pragma unroll
            for (int t = 0; t < 4; ++t) {
                const int ra = wm + (t << 4) + ln;
                a[t] = *(const bf16x8*)&As[(ra << 6) + ((((s << 2) | quad) ^ (ra & 7)) << 3)];
                const int rb = wn + (t << 4) + ln;
                b[t] = *(const bf16x8*)&Bs[(rb << 6) + ((((s << 2) | quad) ^ (rb & 7)) << 3)];
            }
            #pragma unroll
            for (int i = 0; i < 4; ++i)
                #pragma unroll
                for (int j = 0; j < 4; ++j)
                    acc[i][j] = __builtin_amdgcn_mfma_f32_16x16x32_bf16(a[i], b[j], acc[i][j], 0, 0, 0);
        }
        __syncthreads();
    }

    const float4 bv4 = *(const float4*)(bias + n0 + wn + (ln << 2));

    #pragma unroll
    for (int i = 0; i < 4; ++i)
        #pragma unroll
        for (int reg = 0; reg < 4; ++reg) {
            const int m = m0 + wm + (i << 4) + (quad << 2) + reg;
            float4 ov;
            ov.x = acc[i][0][reg] + bv4.x;
            ov.y = acc[i][1][reg] + bv4.y;
            ov.z = acc[i][2][reg] + bv4.z;
            ov.w = acc[i][3][reg] + bv4.w;
            *(float4*)(out + m * 1024 + n0 + wn + (ln << 2)) = ov;
        }
}

// =====================================================================
extern "C" void kernel_launch(void* const* d_in, const int* in_sizes, int n_in,
                              void* d_out, int out_size, void* d_ws, size_t ws_size,
                              hipStream_t stream)
{
    const float* hs   = (const float*)d_in[0];
    const float* mask = (const float*)d_in[1];
    const float* Wq   = (const float*)d_in[2];
    const float* bq   = (const float*)d_in[3];
    const float* Wk   = (const float*)d_in[4];
    const float* bk   = (const float*)d_in[5];
    const float* Wv   = (const float*)d_in[6];
    const float* bv   = (const float*)d_in[7];
    const float* Wo   = (const float*)d_in[8];
    const float* bo   = (const float*)d_in[9];

    unsigned short* ws = (unsigned short*)d_ws;
    const size_t M1 = (size_t)1 << 20;
    unsigned short* hsb   = ws;              // 4M
    unsigned short* wall  = ws + 4 * M1;     // wq|wk|wv
    unsigned short* wob   = ws + 7 * M1;
    unsigned short* qbf   = ws + 8 * M1;
    unsigned short* kbf   = ws + 12 * M1;
    unsigned short* vbf   = ws + 16 * M1;
    unsigned short* vtb   = ws + 20 * M1;
    unsigned short* attnb = ws + 24 * M1;
    float2*         rtab  = (float2*)(ws + 28 * M1);   // 512KB

    convert_kernel<<<8448, 256, 0, stream>>>(hs, Wq, Wk, Wv, Wo, ws, rtab);
    qkv_gemm_kernel<<<dim3(24, 32), 256, 0, stream>>>(hsb, wall, bq, bk, bv, rtab, qbf, kbf, vbf);
    vtrans_kernel<<<1024, 256, 0, stream>>>(vbf, vtb);
    flash_kernel<<<1024, 256, 0, stream>>>(qbf, kbf, vtb, mask, attnb);
    out_gemm_kernel<<<dim3(8, 32), 256, 0, stream>>>(attnb, wob, bo, (float*)d_out);
}